// Round 7
// baseline (755.112 us; speedup 1.0000x reference)
//
#include <hip/hip_runtime.h>
#include <math.h>

#define B_   8
#define N_   3136
#define C_   256
#define NH_  8
#define HD_  32
#define LL_  9
#define PL_  49
#define HF_  682
#define HH   56
#define WW   56
#define MROWS (B_*N_)   // 25088
#define HGLD  704       // hg row stride (bf16); cols 682..703 zeroed (Kt for K=682)
#define F2LD  704       // fc2 weight ld (bf16), zero-padded
#define HBLD  1368      // hbuf row stride (bf16); 16B-aligned rows

typedef short          bf16x8 __attribute__((ext_vector_type(8)));
typedef unsigned short u16x8  __attribute__((ext_vector_type(8)));
typedef float          f32x4  __attribute__((ext_vector_type(4)));
typedef unsigned short u16;

static __device__ __forceinline__ float gelu_f(float x){ return 0.5f*x*(1.0f+erff(x*0.70710678118654752f)); }
static __device__ __forceinline__ u16 f2bf(float f){
  union { float f; unsigned u; } x; x.f = f;
  unsigned r = (x.u + 0x7FFFu + ((x.u >> 16) & 1u)) >> 16;
  return (u16)r;
}
static __device__ __forceinline__ float b2f(u16 u){
  union { unsigned u; float f; } x; x.u = ((unsigned)u) << 16;
  return x.f;
}
// async global->LDS, 16B per lane; lds dest = wave-uniform base + lane*16
static __device__ __forceinline__ void gld_lds16(const u16* g, u16* l){
  __builtin_amdgcn_global_load_lds((const __attribute__((address_space(1))) void*)g,
                                   (__attribute__((address_space(3))) void*)l, 16, 0, 0);
}
static __device__ __forceinline__ float rsum32(float v){
  #pragma unroll
  for (int m=16;m>0;m>>=1) v += __shfl_xor(v,m,32);
  return v;
}
static __device__ __forceinline__ float rsum64(float v){
  #pragma unroll
  for (int m=32;m>0;m>>=1) v += __shfl_xor(v,m,64);
  return v;
}
static __device__ __forceinline__ float rmax64(float v){
  #pragma unroll
  for (int m=32;m>0;m>>=1) v = fmaxf(v,__shfl_xor(v,m,64));
  return v;
}

// ---------------- weight conversion ----------------
__global__ __launch_bounds__(256) void cvt4_kernel(const float* __restrict__ src,
                                                   u16* __restrict__ dst, int n4){
  int i = blockIdx.x*256 + threadIdx.x;
  if (i >= n4) return;
  float4 v = *(const float4*)(src + (size_t)i*4);
  ushort4 o; o.x=f2bf(v.x); o.y=f2bf(v.y); o.z=f2bf(v.z); o.w=f2bf(v.w);
  *(ushort4*)(dst + (size_t)i*4) = o;
}
__global__ __launch_bounds__(256) void cvt_pad_kernel(const float* __restrict__ src,
                                                      u16* __restrict__ dst,
                                                      int rows, int K, int ldw){
  int i = blockIdx.x*256 + threadIdx.x;
  if (i >= rows*ldw) return;
  int r = i/ldw, k = i - r*ldw;
  dst[i] = (k < K) ? f2bf(src[(size_t)r*K + k]) : (u16)0;
}

// ---------------- LayerNorm over C=256 -> bf16 ----------------
__global__ __launch_bounds__(256) void ln_kernel(const float* __restrict__ in,
                                                 const float* __restrict__ w,
                                                 const float* __restrict__ bsh,
                                                 u16* __restrict__ out){
  int row = blockIdx.x, tid = threadIdx.x;
  float v = in[(size_t)row*C_+tid];
  float s = rsum64(v), q = rsum64(v*v);
  __shared__ float s1[4], s2[4];
  if ((tid&63)==0){ s1[tid>>6]=s; s2[tid>>6]=q; }
  __syncthreads();
  float ts=s1[0]+s1[1]+s1[2]+s1[3];
  float tq=s2[0]+s2[1]+s2[2]+s2[3];
  float m = ts*(1.0f/C_);
  float var = tq*(1.0f/C_)-m*m;
  float inv = rsqrtf(var+1e-5f);
  out[(size_t)row*C_+tid] = f2bf((v-m)*inv*w[tid]+bsh[tid]);
}

// ---------------- async bf16 GEMM, 64x64 tile, BK=32 ----------------
// LDS layout: chunk c (cols c*8..c*8+7 of K-block) x 64 rows x 8 u16.
// Requires: lda >= Kt with rows readable to Kt (pads zeroed if Kt>K), same for ldw.
// OUTBF=1 -> bf16 out via LDS-coalesced store (Nt must be mult of 64, M-tail guarded).
template<int ACT, int RES, int OUTBF>
__global__ __launch_bounds__(256) void gemm64a(const u16* __restrict__ A, int lda,
                                               const u16* __restrict__ W, int ldw,
                                               const float* __restrict__ bias,
                                               const float* __restrict__ res,
                                               void* __restrict__ outv,
                                               int M, int Nt, int K){
  __shared__ u16 smem[4608];           // staging 4096 u16; Cs overlay 64x72
  u16* As = smem;                      // [c*512 + r*8]
  u16* Bs = smem + 2048;
  int tid = threadIdx.x, lane = tid & 63, wave = tid >> 6;
  int m0 = blockIdx.x*64, n0 = blockIdx.y*64;
  int wm = (wave>>1)*32, wn = (wave&1)*32;
  int l15 = lane & 15, quad = lane >> 4;
  f32x4 acc[2][2];
  #pragma unroll
  for (int i=0;i<2;i++)
    #pragma unroll
    for (int j=0;j<2;j++) acc[i][j] = (f32x4){0.f,0.f,0.f,0.f};

  const int Kt = (K + 31) & ~31;
  const u16* ga = A + (size_t)(m0 + lane)*lda + wave*8;
  const u16* gb = W + (size_t)(n0 + lane)*ldw + wave*8;
  u16* la = As + wave*512;
  u16* lb = Bs + wave*512;

  for (int k0=0; k0<Kt; k0+=32){
    gld_lds16(ga + k0, la);
    gld_lds16(gb + k0, lb);
    __syncthreads();
    bf16x8 af[2], bfr[2];
    #pragma unroll
    for (int mi=0;mi<2;mi++)
      af[mi] = *(bf16x8*)(&As[quad*512 + (wm + mi*16 + l15)*8]);
    #pragma unroll
    for (int nj=0;nj<2;nj++)
      bfr[nj] = *(bf16x8*)(&Bs[quad*512 + (wn + nj*16 + l15)*8]);
    #pragma unroll
    for (int mi=0;mi<2;mi++)
      #pragma unroll
      for (int nj=0;nj<2;nj++)
        acc[mi][nj] = __builtin_amdgcn_mfma_f32_16x16x32_bf16(af[mi], bfr[nj], acc[mi][nj], 0,0,0);
    __syncthreads();
  }

  if (OUTBF){
    u16* Cs = smem;                    // 64 x 72 (stride pad for store phase)
    #pragma unroll
    for (int nj=0;nj<2;nj++){
      int cc = wn + nj*16 + l15;
      int gc = n0 + cc;
      float bv = (gc < Nt) ? bias[gc] : 0.f;
      #pragma unroll
      for (int mi=0;mi<2;mi++)
        #pragma unroll
        for (int reg=0;reg<4;reg++){
          int rr = wm + mi*16 + quad*4 + reg;
          float v = acc[mi][nj][reg] + bv;
          if (ACT==1) v = gelu_f(v);
          Cs[rr*72 + cc] = f2bf(v);
        }
    }
    __syncthreads();
    int r = tid >> 2, cb = (tid & 3)*16;
    int gr = m0 + r;
    if (gr < M){
      u16* op = (u16*)outv + (size_t)gr*Nt + n0 + cb;
      *(u16x8*)op       = *(u16x8*)&Cs[r*72 + cb];
      *(u16x8*)(op + 8) = *(u16x8*)&Cs[r*72 + cb + 8];
    }
  } else {
    int rbase = quad*4;
    #pragma unroll
    for (int nj=0;nj<2;nj++){
      int gc = n0 + wn + nj*16 + l15;
      if (gc >= Nt) continue;
      float bv = bias[gc];
      #pragma unroll
      for (int mi=0;mi<2;mi++){
        #pragma unroll
        for (int reg=0;reg<4;reg++){
          int gr = m0 + wm + mi*16 + rbase + reg;
          if (gr >= M) continue;
          float v = acc[mi][nj][reg] + bv;
          if (ACT==1) v = gelu_f(v);
          if (RES)   v += res[(size_t)gr*Nt + gc];
          ((float*)outv)[(size_t)gr*Nt + gc] = v;
        }
      }
    }
  }
}

// ---------------- async bf16 GEMM, 128x128 tile, BK=32 (fc1; bf16 out, ldo-padded) ----
__global__ __launch_bounds__(256) void gemm128a(const u16* __restrict__ A, int lda,
                                                const u16* __restrict__ W, int ldw,
                                                const float* __restrict__ bias,
                                                u16* __restrict__ out,
                                                int M, int Nt, int K, int ldo){
  __shared__ u16 smem[8704];           // staging 8192 u16; Cs overlay 64x136
  u16* As = smem;                      // [c*1024 + r*8], r 0..127
  u16* Bs = smem + 4096;
  int tid = threadIdx.x, lane = tid & 63, wave = tid >> 6;
  int m0 = blockIdx.x*128, n0 = blockIdx.y*128;
  int wm = (wave>>1)*64, wn = (wave&1)*64;
  int l15 = lane & 15, quad = lane >> 4;
  f32x4 acc[4][4];
  #pragma unroll
  for (int i=0;i<4;i++)
    #pragma unroll
    for (int j=0;j<4;j++) acc[i][j] = (f32x4){0.f,0.f,0.f,0.f};

  const int Kt = (K + 31) & ~31;
  const u16* ga = A + (size_t)(m0 + lane)*lda + wave*8;
  const u16* gb = W + (size_t)(n0 + lane)*ldw + wave*8;
  u16* la = As + wave*1024;
  u16* lb = Bs + wave*1024;

  for (int k0=0; k0<Kt; k0+=32){
    gld_lds16(ga + k0,            la);
    gld_lds16(ga + 64*lda + k0,   la + 512);
    gld_lds16(gb + k0,            lb);
    gld_lds16(gb + 64*ldw + k0,   lb + 512);
    __syncthreads();
    bf16x8 af[4], bfr[4];
    #pragma unroll
    for (int mi=0;mi<4;mi++)
      af[mi] = *(bf16x8*)(&As[quad*1024 + (wm + mi*16 + l15)*8]);
    #pragma unroll
    for (int nj=0;nj<4;nj++)
      bfr[nj] = *(bf16x8*)(&Bs[quad*1024 + (wn + nj*16 + l15)*8]);
    #pragma unroll
    for (int mi=0;mi<4;mi++)
      #pragma unroll
      for (int nj=0;nj<4;nj++)
        acc[mi][nj] = __builtin_amdgcn_mfma_f32_16x16x32_bf16(af[mi], bfr[nj], acc[mi][nj], 0,0,0);
    __syncthreads();
  }

  u16* Cs = smem;                      // 64 x 136 per pass
  #pragma unroll
  for (int p=0;p<2;p++){
    if (wm == p*64){
      #pragma unroll
      for (int nj=0;nj<4;nj++){
        int cc = wn + nj*16 + l15;
        int gc = n0 + cc;
        float bv = (gc < Nt) ? bias[gc] : 0.f;
        #pragma unroll
        for (int mi=0;mi<4;mi++)
          #pragma unroll
          for (int reg=0;reg<4;reg++){
            int rr = mi*16 + quad*4 + reg;          // 0..63 local
            Cs[rr*136 + cc] = f2bf(acc[mi][nj][reg] + bv);
          }
      }
    }
    __syncthreads();
    int r = tid >> 2, cb = (tid & 3)*32;
    int gr = m0 + p*64 + r;
    if (gr < M){
      u16* op = out + (size_t)gr*ldo + n0;
      #pragma unroll
      for (int k=0;k<4;k++){
        int c0 = cb + k*8;
        if (n0 + c0 + 8 <= ldo)
          *(u16x8*)(op + c0) = *(u16x8*)&Cs[r*136 + c0];
      }
    }
    __syncthreads();
  }
}

// ---------------- q post (bf16 in place) ----------------
__global__ __launch_bounds__(256) void qpost_kernel(u16* __restrict__ q,
                                                    const float* __restrict__ qe,
                                                    const float* __restrict__ temp,
                                                    const float* __restrict__ sls,
                                                    u16* __restrict__ qs_out){
  int row = blockIdx.x, tid = threadIdx.x, h = tid>>5;
  size_t idx = (size_t)row*C_ + tid;
  float v = b2f(q[idx]);
  float ss = rsum32(v*v);
  float qn = v / fmaxf(sqrtf(ss), 1e-12f);
  q[idx] = f2bf(qn);
  float t  = temp[h];
  float sp = log1pf(expf(t));
  float scale = sp * sls[0];
  qs_out[idx] = f2bf((qn + qe[tid])*scale);
}

// ---------------- k l2norm in place (bf16, stride 512) ----------------
__global__ __launch_bounds__(256) void knorm_kernel(u16* __restrict__ kv){
  int row = blockIdx.x, tid = threadIdx.x;
  size_t idx = (size_t)row*512 + tid;
  float v = b2f(kv[idx]);
  float ss = rsum32(v*v);
  kv[idx] = f2bf(v / fmaxf(sqrtf(ss), 1e-12f));
}

// ---------------- 8x8 avg pool + LN (bf16 -> bf16) ----------------
__global__ __launch_bounds__(256) void pool_ln_kernel(const u16* __restrict__ xsr,
                                                      const float* __restrict__ w,
                                                      const float* __restrict__ bsh,
                                                      u16* __restrict__ out){
  int blk = blockIdx.x; int b = blk/PL_; int p = blk%PL_;
  int py = p/7, px = p%7;
  int o = threadIdx.x;
  float s = 0.f;
  for (int iy=0;iy<8;iy++){
    const u16* rowp = xsr + ((size_t)(b*N_ + (py*8+iy)*WW + px*8))*C_ + o;
    #pragma unroll
    for (int ix=0;ix<8;ix++) s += b2f(rowp[(size_t)ix*C_]);
  }
  s *= (1.0f/64.0f);
  float su = rsum64(s), sq = rsum64(s*s);
  __shared__ float s1[4], s2[4];
  if ((o&63)==0){ s1[o>>6]=su; s2[o>>6]=sq; }
  __syncthreads();
  float ts=s1[0]+s1[1]+s1[2]+s1[3];
  float tq=s2[0]+s2[1]+s2[2]+s2[3];
  float m = ts*(1.0f/256.0f), var = tq*(1.0f/256.0f)-m*m;
  float inv = rsqrtf(var+1e-5f);
  out[(size_t)blk*C_+o] = f2bf((s-m)*inv*w[o]+bsh[o]);
}

// ---------------- CPB MLP (f32) ----------------
__global__ __launch_bounds__(256) void cpb_kernel(const float* __restrict__ rct,
                                                  const float* __restrict__ w1,
                                                  const float* __restrict__ b1,
                                                  const float* __restrict__ w2,
                                                  const float* __restrict__ b2v,
                                                  float* __restrict__ cpb){
  __shared__ float r[512];
  int t = blockIdx.x, tid = threadIdx.x;
  float c0 = rct[t*2], c1 = rct[t*2+1];
  for (int j=tid;j<512;j+=256){
    float v = c0*w1[j*2] + c1*w1[j*2+1] + b1[j];
    r[j] = fmaxf(v, 0.f);
  }
  __syncthreads();
  int h = tid>>5, lane = tid&31;
  float s = 0.f;
  for (int j=lane;j<512;j+=32) s += r[j]*w2[h*512+j];
  s = rsum32(s);
  if (lane==0) cpb[t*8+h] = s + b2v[h];
}

// ---------------- local window attention logits (bf16 in) ----------------
__global__ __launch_bounds__(256) void attn_local_kernel(const u16* __restrict__ qs,
                                                         const u16* __restrict__ kv,
                                                         const float* __restrict__ rpb,
                                                         float* __restrict__ attn){
  int blk = blockIdx.x; int b = blk / N_; int n = blk % N_;
  int y = n / WW, x = n % WW;
  int tid = threadIdx.x, h = tid>>5, d = tid&31;
  float q = b2f(qs[(size_t)blk*C_ + tid]);
  float* arow = attn + ((size_t)(b*NH_+h)*N_ + n)*58;
  #pragma unroll
  for (int l=0;l<9;l++){
    int yy = y + l/3 - 1, xx = x + l%3 - 1;
    float kval = 0.f;
    if (yy>=0 && yy<HH && xx>=0 && xx<WW)
      kval = b2f(kv[((size_t)(b*N_ + yy*WW + xx))*512 + tid]);
    float s = rsum32(q*kval);
    if (d==0) arow[l] = s + rpb[h*9+l];
  }
}

// ---------------- pooled attention logits via MFMA ----------------
__global__ __launch_bounds__(256) void attn_pool_mfma(const u16* __restrict__ qs,
                                                      const u16* __restrict__ kvp2,
                                                      const float* __restrict__ cpb,
                                                      const int* __restrict__ ridx,
                                                      float* __restrict__ attn){
  int tid = threadIdx.x, lane = tid & 63, wave = tid >> 6;
  int l15 = lane & 15, quad = lane >> 4;
  int bh = blockIdx.y, b = bh >> 3, h = bh & 7;
  int n0 = (blockIdx.x*4 + wave)*16;
  bf16x8 af = *(const bf16x8*)(qs + ((size_t)(b*N_ + n0 + l15)*C_ + h*32 + quad*8));
  f32x4 acc[4];
  #pragma unroll
  for (int nj=0;nj<4;nj++){
    int p = nj*16 + l15;
    bf16x8 bfr = (bf16x8){0,0,0,0,0,0,0,0};
    if (p < PL_)
      bfr = *(const bf16x8*)(kvp2 + ((size_t)(b*PL_ + p)*512 + h*32 + quad*8));
    f32x4 z = (f32x4){0.f,0.f,0.f,0.f};
    acc[nj] = __builtin_amdgcn_mfma_f32_16x16x32_bf16(af, bfr, z, 0,0,0);
  }
  #pragma unroll
  for (int nj=0;nj<4;nj++){
    int p = nj*16 + l15;
    if (p >= PL_) continue;
    #pragma unroll
    for (int reg=0;reg<4;reg++){
      int n = n0 + quad*4 + reg;
      float bias = cpb[ridx[(size_t)n*PL_ + p]*8 + h];
      attn[((size_t)bh*N_ + n)*58 + 9 + p] = acc[nj][reg] + bias;
    }
  }
}

// ---------------- softmax over 58 ----------------
__global__ __launch_bounds__(256) void softmax_kernel(float* __restrict__ attn){
  int row  = blockIdx.x*4 + (threadIdx.x>>6);
  int lane = threadIdx.x & 63;
  float* p = attn + (size_t)row*58;
  float v = (lane<58) ? p[lane] : -1e30f;
  float mx = rmax64(v);
  float e = (lane<58) ? expf(v-mx) : 0.f;
  float s = rsum64(e);
  if (lane<58) p[lane] = e/s;
}

// ---------------- builders ----------------
__global__ __launch_bounds__(256) void build_w72(const float* __restrict__ lt, u16* __restrict__ w72){
  int r = blockIdx.x, c = threadIdx.x;
  int h = r/9, l = r - h*9;
  w72[(size_t)r*256 + c] = ((c>>5) == h) ? f2bf(lt[((size_t)(h*32 + (c&31)))*9 + l]) : (u16)0;
}
__global__ __launch_bounds__(256) void build_dwwT(const float* __restrict__ dww, float* __restrict__ dwwT){
  int l = blockIdx.x;
  for (int f=threadIdx.x; f<684; f+=256)
    dwwT[(size_t)l*684 + f] = (f < HF_) ? dww[(size_t)f*9 + l] : 0.f;
}

// ---------------- x_local + x_pool -> out (bf16 out) ----------------
__global__ __launch_bounds__(256) void xout_v2(const float* __restrict__ qlt,
                                               const float* __restrict__ attn,
                                               const u16* __restrict__ kv,
                                               const u16* __restrict__ kvp2,
                                               u16* __restrict__ out){
  __shared__ float coef[8][64];
  int row = blockIdx.x; int b = row / N_; int n = row - b*N_;
  int y = n / WW, x = n - y*WW;
  int tid = threadIdx.x;
  for (int i=tid; i<8*58; i+=256){
    int h = i/58, j = i - h*58;
    float v = attn[((size_t)((b<<3)+h)*N_ + n)*58 + j];
    if (j < 9) coef[h][j] = v + qlt[(size_t)row*72 + h*9 + j];
    else       coef[h][j+3] = v;
  }
  __syncthreads();
  int h = tid>>5;
  float acc = 0.f;
  float4 cA = *(float4*)&coef[h][0];
  float4 cB = *(float4*)&coef[h][4];
  float c8  = coef[h][8];
  float lc[9] = {cA.x,cA.y,cA.z,cA.w,cB.x,cB.y,cB.z,cB.w,c8};
  #pragma unroll
  for (int l=0;l<9;l++){
    int yy = y + l/3 - 1, xx = x + l%3 - 1;
    if (yy>=0 && yy<HH && xx>=0 && xx<WW)
      acc += lc[l] * b2f(kv[((size_t)(b*N_ + yy*WW + xx))*512 + 256 + tid]);
  }
  const u16* pb = kvp2 + (size_t)b*PL_*512 + 256 + tid;
  #pragma unroll
  for (int pc=0;pc<12;pc++){
    float4 c4 = *(float4*)&coef[h][12 + pc*4];
    acc += c4.x*b2f(pb[(size_t)(pc*4+0)*512]);
    acc += c4.y*b2f(pb[(size_t)(pc*4+1)*512]);
    acc += c4.z*b2f(pb[(size_t)(pc*4+2)*512]);
    acc += c4.w*b2f(pb[(size_t)(pc*4+3)*512]);
  }
  acc += coef[h][60]*b2f(pb[(size_t)48*512]);
  out[(size_t)row*C_ + tid] = f2bf(acc);
}

// ---------------- depthwise 3x3 + gelu gate (bf16 in/out; hbuf ld=HBLD, hg ld=HGLD) ----
__global__ __launch_bounds__(256) void dwconv_v2(const u16* __restrict__ hsrc,
                                                 const float* __restrict__ dwwT,
                                                 const float* __restrict__ dwb,
                                                 u16* __restrict__ hg){
  int gidx = blockIdx.x*256 + threadIdx.x;
  if (gidx >= MROWS*171) return;
  int pix = gidx/171, g = gidx - pix*171;
  int b = pix / N_, n = pix - b*N_;
  int y = n / WW, x = n - y*WW;
  int f = g*4;
  const u16* hb = hsrc + (size_t)b*N_*HBLD;
  if (g < 170){
    float4 s = *(const float4*)(dwb + f);
    #pragma unroll
    for (int l=0;l<9;l++){
      int yy = y + l/3 - 1, xx = x + l%3 - 1;
      if (yy>=0 && yy<HH && xx>=0 && xx<WW){
        ushort4 hv = *(const ushort4*)(hb + (size_t)(yy*WW+xx)*HBLD + f);
        float4 wv = *(const float4*)(dwwT + (size_t)l*684 + f);
        s.x = fmaf(b2f(hv.x), wv.x, s.x);
        s.y = fmaf(b2f(hv.y), wv.y, s.y);
        s.z = fmaf(b2f(hv.z), wv.z, s.z);
        s.w = fmaf(b2f(hv.w), wv.w, s.w);
      }
    }
    const u16* vp = hsrc + (size_t)pix*HBLD + HF_ + f;
    ushort2 v0 = *(const ushort2*)vp, v1 = *(const ushort2*)(vp+2);
    ushort4 o;
    o.x = f2bf(gelu_f(s.x)*b2f(v0.x)); o.y = f2bf(gelu_f(s.y)*b2f(v0.y));
    o.z = f2bf(gelu_f(s.z)*b2f(v1.x)); o.w = f2bf(gelu_f(s.w)*b2f(v1.y));
    *(ushort4*)(hg + (size_t)pix*HGLD + f) = o;
  } else {
    float r[2];
    #pragma unroll
    for (int c=0;c<2;c++){
      int ff = 680 + c;
      float s = dwb[ff];
      #pragma unroll
      for (int l=0;l<9;l++){
        int yy = y + l/3 - 1, xx = x + l%3 - 1;
        if (yy>=0 && yy<HH && xx>=0 && xx<WW)
          s += b2f(hb[(size_t)(yy*WW+xx)*HBLD + ff]) * dwwT[(size_t)l*684 + ff];
      }
      r[c] = gelu_f(s) * b2f(hsrc[(size_t)pix*HBLD + HF_ + ff]);
    }
    // write 680,681 + zero pad cols 682..703 (fc2 staging reads through lda=704)
    u16* hp = hg + (size_t)pix*HGLD;
    ushort4 o1; o1.x = f2bf(r[0]); o1.y = f2bf(r[1]); o1.z = 0; o1.w = 0;
    *(ushort4*)(hp + 680) = o1;
    ushort4 z4 = {0,0,0,0};
    *(ushort4*)(hp + 684) = z4;
    *(ushort4*)(hp + 688) = z4;
    *(ushort4*)(hp + 692) = z4;
    *(ushort4*)(hp + 696) = z4;
    *(ushort4*)(hp + 700) = z4;
  }
}

extern "C" void kernel_launch(void* const* d_in, const int* in_sizes, int n_in,
                              void* d_out, int out_size, void* d_ws, size_t ws_size,
                              hipStream_t stream) {
  const float* x    = (const float*)d_in[0];
  const float* rct  = (const float*)d_in[1];
  const float* sls  = (const float*)d_in[2];
  const float* n1w  = (const float*)d_in[3];
  const float* n1b  = (const float*)d_in[4];
  const float* q_w  = (const float*)d_in[5];
  const float* q_b  = (const float*)d_in[6];
  const float* kv_w = (const float*)d_in[7];
  const float* kv_b = (const float*)d_in[8];
  const float* temp = (const float*)d_in[9];
  const float* qe   = (const float*)d_in[10];
  const float* rpb  = (const float*)d_in[11];
  const float* lt   = (const float*)d_in[12];
  const float* lb   = (const float*)d_in[13];
  const float* sr_w = (const float*)d_in[14];
  const float* sr_b = (const float*)d_in[15];
  const float* npw  = (const float*)d_in[16];
  const float* npb  = (const float*)d_in[17];
  const float* c1w  = (const float*)d_in[18];
  const float* c1b  = (const float*)d_in[19];
  const float* c2w  = (const float*)d_in[20];
  const float* c2b  = (const float*)d_in[21];
  const float* pw   = (const float*)d_in[22];
  const float* pb   = (const float*)d_in[23];
  const float* n2w  = (const float*)d_in[24];
  const float* n2b  = (const float*)d_in[25];
  const float* f1w  = (const float*)d_in[26];
  const float* f1b  = (const float*)d_in[27];
  const float* dww  = (const float*)d_in[28];
  const float* dwb  = (const float*)d_in[29];
  const float* f2w  = (const float*)d_in[30];
  const float* f2bb = (const float*)d_in[31];
  const int*  ridx  = (const int*)d_in[32];
  float* outp = (float*)d_out;

  char* ws = (char*)d_ws;
  constexpr size_t SZ_BNC2 = (size_t)MROWS*C_*2;        // 12,845,056
  constexpr size_t SZ_KV2  = (size_t)MROWS*512*2;       // 25,690,112
  constexpr size_t SZ_ATTN = (size_t)B_*NH_*N_*58*4;    // 46,563,328
  size_t o_xn   = 0;
  size_t o_qn   = o_xn   + SZ_BNC2;
  size_t o_qs   = o_qn   + SZ_BNC2;
  size_t o_kv   = o_qs   + SZ_BNC2;
  size_t o_attn = o_kv   + SZ_KV2;
  size_t o_xsr  = o_attn + SZ_ATTN;
  size_t o_xpln = o_xsr  + SZ_BNC2;
  size_t o_kvp2 = o_xpln + (size_t)B_*PL_*C_*2;
  size_t o_cpb  = o_kvp2 + (size_t)B_*PL_*512*2;
  size_t o_outb = o_cpb  + (size_t)1024*8*4;
  size_t o_x2   = o_outb + SZ_BNC2;
  size_t o_qlt  = o_x2   + (size_t)MROWS*C_*4;
  size_t o_wq   = o_qlt  + (size_t)MROWS*72*4;
  size_t o_wkv  = o_wq   + (size_t)65536*2;
  size_t o_wsr  = o_wkv  + (size_t)131072*2;
  size_t o_wp   = o_wsr  + (size_t)65536*2;
  size_t o_wf1  = o_wp   + (size_t)65536*2;
  size_t o_wf2  = o_wf1  + (size_t)349184*2;
  size_t o_w72  = o_wf2  + (size_t)256*F2LD*2;
  size_t o_dwwT = o_w72  + (size_t)72*256*2;
  size_t o_h    = o_kv;   // hbuf bf16 25088*1368*2 = 68.6MB over kv+attn (72.25MB) — dead after 14
  size_t o_hg   = 0;      // hg bf16 25088*704*2 = 35.3MB over xn+qn+qs (38.5MB) — all dead by 18

  u16*   xn   = (u16*)(ws + o_xn);
  u16*   qbuf = (u16*)(ws + o_qn);
  u16*   qsc  = (u16*)(ws + o_qs);
  u16*   kv   = (u16*)(ws + o_kv);
  float* attn = (float*)(ws + o_attn);
  u16*   xsr  = (u16*)(ws + o_xsr);
  u16*   xpln = (u16*)(ws + o_xpln);
  u16*   kvp2 = (u16*)(ws + o_kvp2);
  float* cpb  = (float*)(ws + o_cpb);
  u16*   outb = (u16*)(ws + o_outb);
  float* x2   = (float*)(ws + o_x2);
  float* qlt  = (float*)(ws + o_qlt);
  u16*   wq   = (u16*)(ws + o_wq);
  u16*   wkv  = (u16*)(ws + o_wkv);
  u16*   wsr  = (u16*)(ws + o_wsr);
  u16*   wp   = (u16*)(ws + o_wp);
  u16*   wf1  = (u16*)(ws + o_wf1);
  u16*   wf2  = (u16*)(ws + o_wf2);
  u16*   w72  = (u16*)(ws + o_w72);
  float* dwwT = (float*)(ws + o_dwwT);
  u16*   hbuf = (u16*)(ws + o_h);
  u16*   hg   = (u16*)(ws + o_hg);

  // 0. weight conversions (bf16 copies)
  cvt4_kernel<<<(65536/4+255)/256, 256, 0, stream>>>(q_w,  wq,  65536/4);
  cvt4_kernel<<<(131072/4+255)/256,256, 0, stream>>>(kv_w, wkv, 131072/4);
  cvt4_kernel<<<(65536/4+255)/256, 256, 0, stream>>>(sr_w, wsr, 65536/4);
  cvt4_kernel<<<(65536/4+255)/256, 256, 0, stream>>>(pw,   wp,  65536/4);
  cvt4_kernel<<<(349184/4+255)/256,256, 0, stream>>>(f1w,  wf1, 349184/4);
  cvt_pad_kernel<<<(256*F2LD+255)/256, 256, 0, stream>>>(f2w, wf2, 256, HF_, F2LD);
  build_w72<<<72, 256, 0, stream>>>(lt, w72);
  build_dwwT<<<9, 256, 0, stream>>>(dww, dwwT);

  // 1. xn = LN(x) -> bf16
  ln_kernel<<<MROWS, 256, 0, stream>>>(x, n1w, n1b, xn);
  // 2. q = xn @ q_w^T + q_b -> bf16
  gemm64a<0,0,1><<<dim3(392,4), 256, 0, stream>>>(xn, C_, wq, C_, q_b, nullptr, qbuf, MROWS, 256, 256);
  // 3. kv = xn @ kv_w^T + kv_b -> bf16
  gemm64a<0,0,1><<<dim3(392,8), 256, 0, stream>>>(xn, C_, wkv, C_, kv_b, nullptr, kv, MROWS, 512, 256);
  // 4. q_norm (in place) + q_scaled
  qpost_kernel<<<MROWS, 256, 0, stream>>>(qbuf, qe, temp, sls, qsc);
  // 5. k l2norm in place
  knorm_kernel<<<MROWS, 256, 0, stream>>>(kv);
  // 6. x_sr = gelu(xn @ sr_w^T + sr_b) -> bf16
  gemm64a<1,0,1><<<dim3(392,4), 256, 0, stream>>>(xn, C_, wsr, C_, sr_b, nullptr, xsr, MROWS, 256, 256);
  // 7. 8x8 avg pool + LN(normp) -> bf16
  pool_ln_kernel<<<B_*PL_, 256, 0, stream>>>(xsr, npw, npb, xpln);
  // 8. kvp2 = xpln @ kv_w^T + kv_b -> bf16
  gemm64a<0,0,1><<<dim3(7,8), 256, 0, stream>>>(xpln, C_, wkv, C_, kv_b, nullptr, kvp2, B_*PL_, 512, 256);
  // 9. k_pool l2norm in place
  knorm_kernel<<<B_*PL_, 256, 0, stream>>>(kvp2);
  // 10. CPB MLP
  cpb_kernel<<<1024, 256, 0, stream>>>(rct, c1w, c1b, c2w, c2b, cpb);
  // 10b. qlt = qn @ w72^T + lb -> f32
  gemm64a<0,0,0><<<dim3(392,2), 256, 0, stream>>>(qbuf, C_, w72, C_, lb, nullptr, qlt, MROWS, 72, 256);
  // 11. local attention logits
  attn_local_kernel<<<MROWS, 256, 0, stream>>>(qsc, kv, rpb, attn);
  // 12. pooled attention logits (MFMA)
  attn_pool_mfma<<<dim3(49,64), 256, 0, stream>>>(qsc, kvp2, cpb, ridx, attn);
  // 13. softmax over 58
  softmax_kernel<<<(B_*NH_*N_)/4, 256, 0, stream>>>(attn);
  // 14. x_local + x_pool -> outb bf16
  xout_v2<<<MROWS, 256, 0, stream>>>(qlt, attn, kv, kvp2, outb);
  // 15. x2 = x + outb @ proj_w^T + proj_b -> f32
  gemm64a<0,1,0><<<dim3(392,4), 256, 0, stream>>>(outb, C_, wp, C_, pb, x, x2, MROWS, 256, 256);
  // 16. xn2 = LN(x2) -> bf16 (reuses xn)
  ln_kernel<<<MROWS, 256, 0, stream>>>(x2, n2w, n2b, xn);
  // 17. h = xn2 @ fc1_w^T + fc1_b -> bf16 (ldo=HBLD)
  gemm128a<<<dim3(196,11), 256, 0, stream>>>(xn, C_, wf1, C_, f1b, hbuf, MROWS, 1364, 256, HBLD);
  // 18. hg = gelu(dwconv(h1)+dwb) * v -> bf16 (ld HGLD, pads zeroed)
  dwconv_v2<<<(MROWS*171+255)/256, 256, 0, stream>>>(hbuf, dwwT, dwb, hg);
  // 19. out = x2 + hg @ fc2_w^T + fc2_b -> f32
  gemm64a<0,1,0><<<dim3(392,4), 256, 0, stream>>>(hg, HGLD, wf2, F2LD, f2bb, x2, outp, MROWS, 256, HF_);
}

// Round 8
// 699.792 us; speedup vs baseline: 1.0791x; 1.0791x over previous
//
#include <hip/hip_runtime.h>
#include <math.h>

#define B_   8
#define N_   3136
#define C_   256
#define NH_  8
#define HD_  32
#define LL_  9
#define PL_  49
#define HF_  682
#define HH   56
#define WW   56
#define MROWS (B_*N_)   // 25088
#define HGLD  704       // hg row stride (bf16); cols 682..703 zeroed (Kt for K=682)
#define F2LD  704       // fc2 weight ld (bf16), zero-padded
#define HBLD  1368      // hbuf row stride (bf16); 16B-aligned rows

typedef short          bf16x8 __attribute__((ext_vector_type(8)));
typedef unsigned short u16x8  __attribute__((ext_vector_type(8)));
typedef float          f32x4  __attribute__((ext_vector_type(4)));
typedef unsigned short u16;

static __device__ __forceinline__ float gelu_f(float x){ return 0.5f*x*(1.0f+erff(x*0.70710678118654752f)); }
static __device__ __forceinline__ u16 f2bf(float f){
  union { float f; unsigned u; } x; x.f = f;
  unsigned r = (x.u + 0x7FFFu + ((x.u >> 16) & 1u)) >> 16;
  return (u16)r;
}
static __device__ __forceinline__ float b2f(u16 u){
  union { unsigned u; float f; } x; x.u = ((unsigned)u) << 16;
  return x.f;
}
// async global->LDS, 16B per lane; lds dest = wave-uniform base + lane*16
static __device__ __forceinline__ void gld_lds16(const u16* g, u16* l){
  __builtin_amdgcn_global_load_lds((const __attribute__((address_space(1))) void*)g,
                                   (__attribute__((address_space(3))) void*)l, 16, 0, 0);
}
static __device__ __forceinline__ float rsum32(float v){
  #pragma unroll
  for (int m=16;m>0;m>>=1) v += __shfl_xor(v,m,32);
  return v;
}
static __device__ __forceinline__ float rsum64(float v){
  #pragma unroll
  for (int m=32;m>0;m>>=1) v += __shfl_xor(v,m,64);
  return v;
}
static __device__ __forceinline__ float rmax64(float v){
  #pragma unroll
  for (int m=32;m>0;m>>=1) v = fmaxf(v,__shfl_xor(v,m,64));
  return v;
}

// ---------------- weight conversion ----------------
__global__ __launch_bounds__(256) void cvt4_kernel(const float* __restrict__ src,
                                                   u16* __restrict__ dst, int n4){
  int i = blockIdx.x*256 + threadIdx.x;
  if (i >= n4) return;
  float4 v = *(const float4*)(src + (size_t)i*4);
  ushort4 o; o.x=f2bf(v.x); o.y=f2bf(v.y); o.z=f2bf(v.z); o.w=f2bf(v.w);
  *(ushort4*)(dst + (size_t)i*4) = o;
}
__global__ __launch_bounds__(256) void cvt_pad_kernel(const float* __restrict__ src,
                                                      u16* __restrict__ dst,
                                                      int rows, int K, int ldw){
  int i = blockIdx.x*256 + threadIdx.x;
  if (i >= rows*ldw) return;
  int r = i/ldw, k = i - r*ldw;
  dst[i] = (k < K) ? f2bf(src[(size_t)r*K + k]) : (u16)0;
}

// ---------------- LayerNorm over C=256 -> bf16 ----------------
__global__ __launch_bounds__(256) void ln_kernel(const float* __restrict__ in,
                                                 const float* __restrict__ w,
                                                 const float* __restrict__ bsh,
                                                 u16* __restrict__ out){
  int row = blockIdx.x, tid = threadIdx.x;
  float v = in[(size_t)row*C_+tid];
  float s = rsum64(v), q = rsum64(v*v);
  __shared__ float s1[4], s2[4];
  if ((tid&63)==0){ s1[tid>>6]=s; s2[tid>>6]=q; }
  __syncthreads();
  float ts=s1[0]+s1[1]+s1[2]+s1[3];
  float tq=s2[0]+s2[1]+s2[2]+s2[3];
  float m = ts*(1.0f/C_);
  float var = tq*(1.0f/C_)-m*m;
  float inv = rsqrtf(var+1e-5f);
  out[(size_t)row*C_+tid] = f2bf((v-m)*inv*w[tid]+bsh[tid]);
}

// ---------------- bf16-in GEMM, 64x64 tile, BK=32 (round-6 sync staging) ----------------
// A[M][lda] bf16 (cols K..lda-1 zeroed), W[Nt][ldw] bf16 (cols K..ldw-1 zeroed).
template<int ACT, int RES, int OUTBF>
__global__ __launch_bounds__(256) void gemm64b(const u16* __restrict__ A, int lda,
                                               const u16* __restrict__ W, int ldw,
                                               const float* __restrict__ bias,
                                               const float* __restrict__ res,
                                               void* __restrict__ outv,
                                               int M, int Nt, int K){
  constexpr int LDT = 40;
  __shared__ u16 As[64*LDT];
  __shared__ u16 Bs[64*LDT];
  int tid = threadIdx.x, lane = tid & 63;
  int wave = tid >> 6;
  int m0 = blockIdx.x*64, n0 = blockIdx.y*64;
  int wm = (wave>>1)*32, wn = (wave&1)*32;
  f32x4 acc[2][2];
  #pragma unroll
  for (int i=0;i<2;i++)
    #pragma unroll
    for (int j=0;j<2;j++) acc[i][j] = (f32x4){0.f,0.f,0.f,0.f};

  const int Kt = (K + 31) & ~31;
  const int l15 = lane & 15, quad = lane >> 4;
  int r  = tid >> 2;             // 0..63
  int c8 = (tid & 3) * 8;        // 0,8,16,24

  for (int k0=0; k0<Kt; k0+=32){
    int gk = k0 + c8;
    u16x8 av = (u16x8){0,0,0,0,0,0,0,0};
    if (m0 + r < M && gk + 8 <= lda)
      av = *(const u16x8*)(A + (size_t)(m0+r)*lda + gk);
    *(u16x8*)(&As[r*LDT + c8]) = av;
    u16x8 bv = (u16x8){0,0,0,0,0,0,0,0};
    if (n0 + r < Nt && gk + 8 <= ldw)
      bv = *(const u16x8*)(W + (size_t)(n0+r)*ldw + gk);
    *(u16x8*)(&Bs[r*LDT + c8]) = bv;
    __syncthreads();
    bf16x8 af[2], bfr[2];
    #pragma unroll
    for (int mi=0;mi<2;mi++)
      af[mi] = *(bf16x8*)(&As[(wm + mi*16 + l15)*LDT + quad*8]);
    #pragma unroll
    for (int nj=0;nj<2;nj++)
      bfr[nj] = *(bf16x8*)(&Bs[(wn + nj*16 + l15)*LDT + quad*8]);
    #pragma unroll
    for (int mi=0;mi<2;mi++)
      #pragma unroll
      for (int nj=0;nj<2;nj++)
        acc[mi][nj] = __builtin_amdgcn_mfma_f32_16x16x32_bf16(af[mi], bfr[nj], acc[mi][nj], 0,0,0);
    __syncthreads();
  }
  int rbase = quad*4;
  #pragma unroll
  for (int nj=0;nj<2;nj++){
    int gc = n0 + wn + nj*16 + l15;
    if (gc >= Nt) continue;
    float bv = bias[gc];
    #pragma unroll
    for (int mi=0;mi<2;mi++){
      #pragma unroll
      for (int reg=0;reg<4;reg++){
        int gr = m0 + wm + mi*16 + rbase + reg;
        if (gr >= M) continue;
        float v = acc[mi][nj][reg] + bv;
        if (ACT==1) v = gelu_f(v);
        if (RES)   v += res[(size_t)gr*Nt + gc];
        if (OUTBF) ((u16*)outv)[(size_t)gr*Nt + gc] = f2bf(v);
        else       ((float*)outv)[(size_t)gr*Nt + gc] = v;
      }
    }
  }
}

// ---------------- async bf16 GEMM, 128x128 tile, BK=32 (fc1; bf16 out, ldo-padded) ----
__global__ __launch_bounds__(256) void gemm128a(const u16* __restrict__ A, int lda,
                                                const u16* __restrict__ W, int ldw,
                                                const float* __restrict__ bias,
                                                u16* __restrict__ out,
                                                int M, int Nt, int K, int ldo){
  __shared__ u16 smem[8704];           // staging 8192 u16; Cs overlay 64x136
  u16* As = smem;                      // [c*1024 + r*8], r 0..127
  u16* Bs = smem + 4096;
  int tid = threadIdx.x, lane = tid & 63, wave = tid >> 6;
  int m0 = blockIdx.x*128, n0 = blockIdx.y*128;
  int wm = (wave>>1)*64, wn = (wave&1)*64;
  int l15 = lane & 15, quad = lane >> 4;
  f32x4 acc[4][4];
  #pragma unroll
  for (int i=0;i<4;i++)
    #pragma unroll
    for (int j=0;j<4;j++) acc[i][j] = (f32x4){0.f,0.f,0.f,0.f};

  const int Kt = (K + 31) & ~31;
  const u16* ga = A + (size_t)(m0 + lane)*lda + wave*8;
  const u16* gb = W + (size_t)(n0 + lane)*ldw + wave*8;
  u16* la = As + wave*1024;
  u16* lb = Bs + wave*1024;

  for (int k0=0; k0<Kt; k0+=32){
    gld_lds16(ga + k0,            la);
    gld_lds16(ga + 64*lda + k0,   la + 512);
    gld_lds16(gb + k0,            lb);
    gld_lds16(gb + 64*ldw + k0,   lb + 512);
    __syncthreads();
    bf16x8 af[4], bfr[4];
    #pragma unroll
    for (int mi=0;mi<4;mi++)
      af[mi] = *(bf16x8*)(&As[quad*1024 + (wm + mi*16 + l15)*8]);
    #pragma unroll
    for (int nj=0;nj<4;nj++)
      bfr[nj] = *(bf16x8*)(&Bs[quad*1024 + (wn + nj*16 + l15)*8]);
    #pragma unroll
    for (int mi=0;mi<4;mi++)
      #pragma unroll
      for (int nj=0;nj<4;nj++)
        acc[mi][nj] = __builtin_amdgcn_mfma_f32_16x16x32_bf16(af[mi], bfr[nj], acc[mi][nj], 0,0,0);
    __syncthreads();
  }

  u16* Cs = smem;                      // 64 x 136 per pass
  #pragma unroll
  for (int p=0;p<2;p++){
    if (wm == p*64){
      #pragma unroll
      for (int nj=0;nj<4;nj++){
        int cc = wn + nj*16 + l15;
        int gc = n0 + cc;
        float bv = (gc < Nt) ? bias[gc] : 0.f;
        #pragma unroll
        for (int mi=0;mi<4;mi++)
          #pragma unroll
          for (int reg=0;reg<4;reg++){
            int rr = mi*16 + quad*4 + reg;          // 0..63 local
            Cs[rr*136 + cc] = f2bf(acc[mi][nj][reg] + bv);
          }
      }
    }
    __syncthreads();
    int r = tid >> 2, cb = (tid & 3)*32;
    int gr = m0 + p*64 + r;
    if (gr < M){
      u16* op = out + (size_t)gr*ldo + n0;
      #pragma unroll
      for (int k=0;k<4;k++){
        int c0 = cb + k*8;
        if (n0 + c0 + 8 <= ldo)
          *(u16x8*)(op + c0) = *(u16x8*)&Cs[r*136 + c0];
      }
    }
    __syncthreads();
  }
}

// ---------------- q post (bf16 in place) ----------------
__global__ __launch_bounds__(256) void qpost_kernel(u16* __restrict__ q,
                                                    const float* __restrict__ qe,
                                                    const float* __restrict__ temp,
                                                    const float* __restrict__ sls,
                                                    u16* __restrict__ qs_out){
  int row = blockIdx.x, tid = threadIdx.x, h = tid>>5;
  size_t idx = (size_t)row*C_ + tid;
  float v = b2f(q[idx]);
  float ss = rsum32(v*v);
  float qn = v / fmaxf(sqrtf(ss), 1e-12f);
  q[idx] = f2bf(qn);
  float t  = temp[h];
  float sp = log1pf(expf(t));
  float scale = sp * sls[0];
  qs_out[idx] = f2bf((qn + qe[tid])*scale);
}

// ---------------- k l2norm in place (bf16, stride 512) ----------------
__global__ __launch_bounds__(256) void knorm_kernel(u16* __restrict__ kv){
  int row = blockIdx.x, tid = threadIdx.x;
  size_t idx = (size_t)row*512 + tid;
  float v = b2f(kv[idx]);
  float ss = rsum32(v*v);
  kv[idx] = f2bf(v / fmaxf(sqrtf(ss), 1e-12f));
}

// ---------------- 8x8 avg pool + LN (bf16 -> bf16) ----------------
__global__ __launch_bounds__(256) void pool_ln_kernel(const u16* __restrict__ xsr,
                                                      const float* __restrict__ w,
                                                      const float* __restrict__ bsh,
                                                      u16* __restrict__ out){
  int blk = blockIdx.x; int b = blk/PL_; int p = blk%PL_;
  int py = p/7, px = p%7;
  int o = threadIdx.x;
  float s = 0.f;
  for (int iy=0;iy<8;iy++){
    const u16* rowp = xsr + ((size_t)(b*N_ + (py*8+iy)*WW + px*8))*C_ + o;
    #pragma unroll
    for (int ix=0;ix<8;ix++) s += b2f(rowp[(size_t)ix*C_]);
  }
  s *= (1.0f/64.0f);
  float su = rsum64(s), sq = rsum64(s*s);
  __shared__ float s1[4], s2[4];
  if ((o&63)==0){ s1[o>>6]=su; s2[o>>6]=sq; }
  __syncthreads();
  float ts=s1[0]+s1[1]+s1[2]+s1[3];
  float tq=s2[0]+s2[1]+s2[2]+s2[3];
  float m = ts*(1.0f/256.0f), var = tq*(1.0f/256.0f)-m*m;
  float inv = rsqrtf(var+1e-5f);
  out[(size_t)blk*C_+o] = f2bf((s-m)*inv*w[o]+bsh[o]);
}

// ---------------- CPB MLP (f32) ----------------
__global__ __launch_bounds__(256) void cpb_kernel(const float* __restrict__ rct,
                                                  const float* __restrict__ w1,
                                                  const float* __restrict__ b1,
                                                  const float* __restrict__ w2,
                                                  const float* __restrict__ b2v,
                                                  float* __restrict__ cpb){
  __shared__ float r[512];
  int t = blockIdx.x, tid = threadIdx.x;
  float c0 = rct[t*2], c1 = rct[t*2+1];
  for (int j=tid;j<512;j+=256){
    float v = c0*w1[j*2] + c1*w1[j*2+1] + b1[j];
    r[j] = fmaxf(v, 0.f);
  }
  __syncthreads();
  int h = tid>>5, lane = tid&31;
  float s = 0.f;
  for (int j=lane;j<512;j+=32) s += r[j]*w2[h*512+j];
  s = rsum32(s);
  if (lane==0) cpb[t*8+h] = s + b2v[h];
}

// ---------------- local window attention logits (bf16 in) ----------------
__global__ __launch_bounds__(256) void attn_local_kernel(const u16* __restrict__ qs,
                                                         const u16* __restrict__ kv,
                                                         const float* __restrict__ rpb,
                                                         float* __restrict__ attn){
  int blk = blockIdx.x; int b = blk / N_; int n = blk % N_;
  int y = n / WW, x = n % WW;
  int tid = threadIdx.x, h = tid>>5, d = tid&31;
  float q = b2f(qs[(size_t)blk*C_ + tid]);
  float* arow = attn + ((size_t)(b*NH_+h)*N_ + n)*58;
  #pragma unroll
  for (int l=0;l<9;l++){
    int yy = y + l/3 - 1, xx = x + l%3 - 1;
    float kval = 0.f;
    if (yy>=0 && yy<HH && xx>=0 && xx<WW)
      kval = b2f(kv[((size_t)(b*N_ + yy*WW + xx))*512 + tid]);
    float s = rsum32(q*kval);
    if (d==0) arow[l] = s + rpb[h*9+l];
  }
}

// ---------------- pooled attention logits via MFMA ----------------
__global__ __launch_bounds__(256) void attn_pool_mfma(const u16* __restrict__ qs,
                                                      const u16* __restrict__ kvp2,
                                                      const float* __restrict__ cpb,
                                                      const int* __restrict__ ridx,
                                                      float* __restrict__ attn){
  int tid = threadIdx.x, lane = tid & 63, wave = tid >> 6;
  int l15 = lane & 15, quad = lane >> 4;
  int bh = blockIdx.y, b = bh >> 3, h = bh & 7;
  int n0 = (blockIdx.x*4 + wave)*16;
  bf16x8 af = *(const bf16x8*)(qs + ((size_t)(b*N_ + n0 + l15)*C_ + h*32 + quad*8));
  f32x4 acc[4];
  #pragma unroll
  for (int nj=0;nj<4;nj++){
    int p = nj*16 + l15;
    bf16x8 bfr = (bf16x8){0,0,0,0,0,0,0,0};
    if (p < PL_)
      bfr = *(const bf16x8*)(kvp2 + ((size_t)(b*PL_ + p)*512 + h*32 + quad*8));
    f32x4 z = (f32x4){0.f,0.f,0.f,0.f};
    acc[nj] = __builtin_amdgcn_mfma_f32_16x16x32_bf16(af, bfr, z, 0,0,0);
  }
  #pragma unroll
  for (int nj=0;nj<4;nj++){
    int p = nj*16 + l15;
    if (p >= PL_) continue;
    #pragma unroll
    for (int reg=0;reg<4;reg++){
      int n = n0 + quad*4 + reg;
      float bias = cpb[ridx[(size_t)n*PL_ + p]*8 + h];
      attn[((size_t)bh*N_ + n)*58 + 9 + p] = acc[nj][reg] + bias;
    }
  }
}

// ---------------- softmax over 58 ----------------
__global__ __launch_bounds__(256) void softmax_kernel(float* __restrict__ attn){
  int row  = blockIdx.x*4 + (threadIdx.x>>6);
  int lane = threadIdx.x & 63;
  float* p = attn + (size_t)row*58;
  float v = (lane<58) ? p[lane] : -1e30f;
  float mx = rmax64(v);
  float e = (lane<58) ? expf(v-mx) : 0.f;
  float s = rsum64(e);
  if (lane<58) p[lane] = e/s;
}

// ---------------- builders ----------------
__global__ __launch_bounds__(256) void build_w72(const float* __restrict__ lt, u16* __restrict__ w72){
  int r = blockIdx.x, c = threadIdx.x;
  int h = r/9, l = r - h*9;
  w72[(size_t)r*256 + c] = ((c>>5) == h) ? f2bf(lt[((size_t)(h*32 + (c&31)))*9 + l]) : (u16)0;
}
__global__ __launch_bounds__(256) void build_dwwT(const float* __restrict__ dww, float* __restrict__ dwwT){
  int l = blockIdx.x;
  for (int f=threadIdx.x; f<684; f+=256)
    dwwT[(size_t)l*684 + f] = (f < HF_) ? dww[(size_t)f*9 + l] : 0.f;
}

// ---------------- x_local + x_pool -> out (bf16 out) ----------------
__global__ __launch_bounds__(256) void xout_v2(const float* __restrict__ qlt,
                                               const float* __restrict__ attn,
                                               const u16* __restrict__ kv,
                                               const u16* __restrict__ kvp2,
                                               u16* __restrict__ out){
  __shared__ float coef[8][64];
  int row = blockIdx.x; int b = row / N_; int n = row - b*N_;
  int y = n / WW, x = n - y*WW;
  int tid = threadIdx.x;
  for (int i=tid; i<8*58; i+=256){
    int h = i/58, j = i - h*58;
    float v = attn[((size_t)((b<<3)+h)*N_ + n)*58 + j];
    if (j < 9) coef[h][j] = v + qlt[(size_t)row*72 + h*9 + j];
    else       coef[h][j+3] = v;
  }
  __syncthreads();
  int h = tid>>5;
  float acc = 0.f;
  float4 cA = *(float4*)&coef[h][0];
  float4 cB = *(float4*)&coef[h][4];
  float c8  = coef[h][8];
  float lc[9] = {cA.x,cA.y,cA.z,cA.w,cB.x,cB.y,cB.z,cB.w,c8};
  #pragma unroll
  for (int l=0;l<9;l++){
    int yy = y + l/3 - 1, xx = x + l%3 - 1;
    if (yy>=0 && yy<HH && xx>=0 && xx<WW)
      acc += lc[l] * b2f(kv[((size_t)(b*N_ + yy*WW + xx))*512 + 256 + tid]);
  }
  const u16* pb = kvp2 + (size_t)b*PL_*512 + 256 + tid;
  #pragma unroll
  for (int pc=0;pc<12;pc++){
    float4 c4 = *(float4*)&coef[h][12 + pc*4];
    acc += c4.x*b2f(pb[(size_t)(pc*4+0)*512]);
    acc += c4.y*b2f(pb[(size_t)(pc*4+1)*512]);
    acc += c4.z*b2f(pb[(size_t)(pc*4+2)*512]);
    acc += c4.w*b2f(pb[(size_t)(pc*4+3)*512]);
  }
  acc += coef[h][60]*b2f(pb[(size_t)48*512]);
  out[(size_t)row*C_ + tid] = f2bf(acc);
}

// ---------------- depthwise 3x3 + gelu gate, XCD-confined per batch ----------------
// grid (8, 2096): linear block id = b + 8*band -> id%8 == b, so each batch image
// (and its 3-row reuse window) stays on one XCD's L2.
__global__ __launch_bounds__(256) void dwconv_v3(const u16* __restrict__ hsrc,
                                                 const float* __restrict__ dwwT,
                                                 const float* __restrict__ dwb,
                                                 u16* __restrict__ hg){
  int b = blockIdx.x;
  int idx = blockIdx.y*256 + threadIdx.x;
  if (idx >= N_*171) return;
  int n = idx/171, g = idx - n*171;
  int pix = b*N_ + n;
  int y = n / WW, x = n - y*WW;
  int f = g*4;
  const u16* hb = hsrc + (size_t)b*N_*HBLD;
  if (g < 170){
    float4 s = *(const float4*)(dwb + f);
    #pragma unroll
    for (int l=0;l<9;l++){
      int yy = y + l/3 - 1, xx = x + l%3 - 1;
      if (yy>=0 && yy<HH && xx>=0 && xx<WW){
        ushort4 hv = *(const ushort4*)(hb + (size_t)(yy*WW+xx)*HBLD + f);
        float4 wv = *(const float4*)(dwwT + (size_t)l*684 + f);
        s.x = fmaf(b2f(hv.x), wv.x, s.x);
        s.y = fmaf(b2f(hv.y), wv.y, s.y);
        s.z = fmaf(b2f(hv.z), wv.z, s.z);
        s.w = fmaf(b2f(hv.w), wv.w, s.w);
      }
    }
    const u16* vp = hsrc + (size_t)pix*HBLD + HF_ + f;
    ushort2 v0 = *(const ushort2*)vp, v1 = *(const ushort2*)(vp+2);
    ushort4 o;
    o.x = f2bf(gelu_f(s.x)*b2f(v0.x)); o.y = f2bf(gelu_f(s.y)*b2f(v0.y));
    o.z = f2bf(gelu_f(s.z)*b2f(v1.x)); o.w = f2bf(gelu_f(s.w)*b2f(v1.y));
    *(ushort4*)(hg + (size_t)pix*HGLD + f) = o;
  } else {
    float r[2];
    #pragma unroll
    for (int c=0;c<2;c++){
      int ff = 680 + c;
      float s = dwb[ff];
      #pragma unroll
      for (int l=0;l<9;l++){
        int yy = y + l/3 - 1, xx = x + l%3 - 1;
        if (yy>=0 && yy<HH && xx>=0 && xx<WW)
          s += b2f(hb[(size_t)(yy*WW+xx)*HBLD + ff]) * dwwT[(size_t)l*684 + ff];
      }
      r[c] = gelu_f(s) * b2f(hsrc[(size_t)pix*HBLD + HF_ + ff]);
    }
    u16* hp = hg + (size_t)pix*HGLD;
    ushort4 o1; o1.x = f2bf(r[0]); o1.y = f2bf(r[1]); o1.z = 0; o1.w = 0;
    *(ushort4*)(hp + 680) = o1;
    ushort4 z4 = {0,0,0,0};
    *(ushort4*)(hp + 684) = z4;
    *(ushort4*)(hp + 688) = z4;
    *(ushort4*)(hp + 692) = z4;
    *(ushort4*)(hp + 696) = z4;
    *(ushort4*)(hp + 700) = z4;
  }
}

extern "C" void kernel_launch(void* const* d_in, const int* in_sizes, int n_in,
                              void* d_out, int out_size, void* d_ws, size_t ws_size,
                              hipStream_t stream) {
  const float* x    = (const float*)d_in[0];
  const float* rct  = (const float*)d_in[1];
  const float* sls  = (const float*)d_in[2];
  const float* n1w  = (const float*)d_in[3];
  const float* n1b  = (const float*)d_in[4];
  const float* q_w  = (const float*)d_in[5];
  const float* q_b  = (const float*)d_in[6];
  const float* kv_w = (const float*)d_in[7];
  const float* kv_b = (const float*)d_in[8];
  const float* temp = (const float*)d_in[9];
  const float* qe   = (const float*)d_in[10];
  const float* rpb  = (const float*)d_in[11];
  const float* lt   = (const float*)d_in[12];
  const float* lb   = (const float*)d_in[13];
  const float* sr_w = (const float*)d_in[14];
  const float* sr_b = (const float*)d_in[15];
  const float* npw  = (const float*)d_in[16];
  const float* npb  = (const float*)d_in[17];
  const float* c1w  = (const float*)d_in[18];
  const float* c1b  = (const float*)d_in[19];
  const float* c2w  = (const float*)d_in[20];
  const float* c2b  = (const float*)d_in[21];
  const float* pw   = (const float*)d_in[22];
  const float* pb   = (const float*)d_in[23];
  const float* n2w  = (const float*)d_in[24];
  const float* n2b  = (const float*)d_in[25];
  const float* f1w  = (const float*)d_in[26];
  const float* f1b  = (const float*)d_in[27];
  const float* dww  = (const float*)d_in[28];
  const float* dwb  = (const float*)d_in[29];
  const float* f2w  = (const float*)d_in[30];
  const float* f2bb = (const float*)d_in[31];
  const int*  ridx  = (const int*)d_in[32];
  float* outp = (float*)d_out;

  char* ws = (char*)d_ws;
  constexpr size_t SZ_BNC2 = (size_t)MROWS*C_*2;
  constexpr size_t SZ_KV2  = (size_t)MROWS*512*2;
  constexpr size_t SZ_ATTN = (size_t)B_*NH_*N_*58*4;
  size_t o_xn   = 0;
  size_t o_qn   = o_xn   + SZ_BNC2;
  size_t o_qs   = o_qn   + SZ_BNC2;
  size_t o_kv   = o_qs   + SZ_BNC2;
  size_t o_attn = o_kv   + SZ_KV2;
  size_t o_xsr  = o_attn + SZ_ATTN;
  size_t o_xpln = o_xsr  + SZ_BNC2;
  size_t o_kvp2 = o_xpln + (size_t)B_*PL_*C_*2;
  size_t o_cpb  = o_kvp2 + (size_t)B_*PL_*512*2;
  size_t o_outb = o_cpb  + (size_t)1024*8*4;
  size_t o_x2   = o_outb + SZ_BNC2;
  size_t o_qlt  = o_x2   + (size_t)MROWS*C_*4;
  size_t o_wq   = o_qlt  + (size_t)MROWS*72*4;
  size_t o_wkv  = o_wq   + (size_t)65536*2;
  size_t o_wsr  = o_wkv  + (size_t)131072*2;
  size_t o_wp   = o_wsr  + (size_t)65536*2;
  size_t o_wf1  = o_wp   + (size_t)65536*2;
  size_t o_wf2  = o_wf1  + (size_t)349184*2;
  size_t o_w72  = o_wf2  + (size_t)256*F2LD*2;
  size_t o_dwwT = o_w72  + (size_t)72*256*2;
  size_t o_h    = o_kv;   // hbuf bf16 25088*1368*2 = 68.6MB over kv+attn (72.25MB) — dead after 14
  size_t o_hg   = 0;      // hg bf16 25088*704*2 = 35.3MB over xn+qn+qs (38.5MB) — all dead by 18

  u16*   xn   = (u16*)(ws + o_xn);
  u16*   qbuf = (u16*)(ws + o_qn);
  u16*   qsc  = (u16*)(ws + o_qs);
  u16*   kv   = (u16*)(ws + o_kv);
  float* attn = (float*)(ws + o_attn);
  u16*   xsr  = (u16*)(ws + o_xsr);
  u16*   xpln = (u16*)(ws + o_xpln);
  u16*   kvp2 = (u16*)(ws + o_kvp2);
  float* cpb  = (float*)(ws + o_cpb);
  u16*   outb = (u16*)(ws + o_outb);
  float* x2   = (float*)(ws + o_x2);
  float* qlt  = (float*)(ws + o_qlt);
  u16*   wq   = (u16*)(ws + o_wq);
  u16*   wkv  = (u16*)(ws + o_wkv);
  u16*   wsr  = (u16*)(ws + o_wsr);
  u16*   wp   = (u16*)(ws + o_wp);
  u16*   wf1  = (u16*)(ws + o_wf1);
  u16*   wf2  = (u16*)(ws + o_wf2);
  u16*   w72  = (u16*)(ws + o_w72);
  float* dwwT = (float*)(ws + o_dwwT);
  u16*   hbuf = (u16*)(ws + o_h);
  u16*   hg   = (u16*)(ws + o_hg);

  // 0. weight conversions (bf16 copies)
  cvt4_kernel<<<(65536/4+255)/256, 256, 0, stream>>>(q_w,  wq,  65536/4);
  cvt4_kernel<<<(131072/4+255)/256,256, 0, stream>>>(kv_w, wkv, 131072/4);
  cvt4_kernel<<<(65536/4+255)/256, 256, 0, stream>>>(sr_w, wsr, 65536/4);
  cvt4_kernel<<<(65536/4+255)/256, 256, 0, stream>>>(pw,   wp,  65536/4);
  cvt4_kernel<<<(349184/4+255)/256,256, 0, stream>>>(f1w,  wf1, 349184/4);
  cvt_pad_kernel<<<(256*F2LD+255)/256, 256, 0, stream>>>(f2w, wf2, 256, HF_, F2LD);
  build_w72<<<72, 256, 0, stream>>>(lt, w72);
  build_dwwT<<<9, 256, 0, stream>>>(dww, dwwT);

  // 1. xn = LN(x) -> bf16
  ln_kernel<<<MROWS, 256, 0, stream>>>(x, n1w, n1b, xn);
  // 2. q = xn @ q_w^T + q_b -> bf16
  gemm64b<0,0,1><<<dim3(392,4), 256, 0, stream>>>(xn, C_, wq, C_, q_b, nullptr, qbuf, MROWS, 256, 256);
  // 3. kv = xn @ kv_w^T + kv_b -> bf16
  gemm64b<0,0,1><<<dim3(392,8), 256, 0, stream>>>(xn, C_, wkv, C_, kv_b, nullptr, kv, MROWS, 512, 256);
  // 4. q_norm (in place) + q_scaled
  qpost_kernel<<<MROWS, 256, 0, stream>>>(qbuf, qe, temp, sls, qsc);
  // 5. k l2norm in place
  knorm_kernel<<<MROWS, 256, 0, stream>>>(kv);
  // 6. x_sr = gelu(xn @ sr_w^T + sr_b) -> bf16
  gemm64b<1,0,1><<<dim3(392,4), 256, 0, stream>>>(xn, C_, wsr, C_, sr_b, nullptr, xsr, MROWS, 256, 256);
  // 7. 8x8 avg pool + LN(normp) -> bf16
  pool_ln_kernel<<<B_*PL_, 256, 0, stream>>>(xsr, npw, npb, xpln);
  // 8. kvp2 = xpln @ kv_w^T + kv_b -> bf16
  gemm64b<0,0,1><<<dim3(7,8), 256, 0, stream>>>(xpln, C_, wkv, C_, kv_b, nullptr, kvp2, B_*PL_, 512, 256);
  // 9. k_pool l2norm in place
  knorm_kernel<<<B_*PL_, 256, 0, stream>>>(kvp2);
  // 10. CPB MLP
  cpb_kernel<<<1024, 256, 0, stream>>>(rct, c1w, c1b, c2w, c2b, cpb);
  // 10b. qlt = qn @ w72^T + lb -> f32
  gemm64b<0,0,0><<<dim3(392,2), 256, 0, stream>>>(qbuf, C_, w72, C_, lb, nullptr, qlt, MROWS, 72, 256);
  // 11. local attention logits
  attn_local_kernel<<<MROWS, 256, 0, stream>>>(qsc, kv, rpb, attn);
  // 12. pooled attention logits (MFMA)
  attn_pool_mfma<<<dim3(49,64), 256, 0, stream>>>(qsc, kvp2, cpb, ridx, attn);
  // 13. softmax over 58
  softmax_kernel<<<(B_*NH_*N_)/4, 256, 0, stream>>>(attn);
  // 14. x_local + x_pool -> outb bf16
  xout_v2<<<MROWS, 256, 0, stream>>>(qlt, attn, kv, kvp2, outb);
  // 15. x2 = x + outb @ proj_w^T + proj_b -> f32
  gemm64b<0,1,0><<<dim3(392,4), 256, 0, stream>>>(outb, C_, wp, C_, pb, x, x2, MROWS, 256, 256);
  // 16. xn2 = LN(x2) -> bf16 (reuses xn)
  ln_kernel<<<MROWS, 256, 0, stream>>>(x2, n2w, n2b, xn);
  // 17. h = xn2 @ fc1_w^T + fc1_b -> bf16 (ldo=HBLD, async 128-tile)
  gemm128a<<<dim3(196,11), 256, 0, stream>>>(xn, C_, wf1, C_, f1b, hbuf, MROWS, 1364, 256, HBLD);
  // 18. hg = gelu(dwconv(h1)+dwb) * v -> bf16 (XCD-confined grid)
  dwconv_v3<<<dim3(8, (N_*171+255)/256), 256, 0, stream>>>(hbuf, dwwT, dwb, hg);
  // 19. out = x2 + hg @ fc2_w^T + fc2_b -> f32
  gemm64b<0,1,0><<<dim3(392,4), 256, 0, stream>>>(hg, HGLD, wf2, F2LD, f2bb, x2, outp, MROWS, 256, HF_);
}

// Round 9
// 635.059 us; speedup vs baseline: 1.1890x; 1.1019x over previous
//
#include <hip/hip_runtime.h>
#include <math.h>

#define B_   8
#define N_   3136
#define C_   256
#define NH_  8
#define HD_  32
#define LL_  9
#define PL_  49
#define HF_  682
#define HH   56
#define WW   56
#define MROWS (B_*N_)   // 25088
#define HGLD  704       // hg row stride (bf16); cols 682..703 zeroed (Kt for K=682)
#define F2LD  704       // fc2 weight ld (bf16), zero-padded
#define HBLD  1368      // hbuf row stride (bf16); 16B-aligned rows

typedef short          bf16x8 __attribute__((ext_vector_type(8)));
typedef unsigned short u16x8  __attribute__((ext_vector_type(8)));
typedef float          f32x4  __attribute__((ext_vector_type(4)));
typedef unsigned short u16;

static __device__ __forceinline__ float gelu_f(float x){ return 0.5f*x*(1.0f+erff(x*0.70710678118654752f)); }
static __device__ __forceinline__ u16 f2bf(float f){
  union { float f; unsigned u; } x; x.f = f;
  unsigned r = (x.u + 0x7FFFu + ((x.u >> 16) & 1u)) >> 16;
  return (u16)r;
}
static __device__ __forceinline__ float b2f(u16 u){
  union { unsigned u; float f; } x; x.u = ((unsigned)u) << 16;
  return x.f;
}
// async global->LDS, 16B per lane; lds dest = wave-uniform base + lane*16
static __device__ __forceinline__ void gld_lds16(const u16* g, u16* l){
  __builtin_amdgcn_global_load_lds((const __attribute__((address_space(1))) void*)g,
                                   (__attribute__((address_space(3))) void*)l, 16, 0, 0);
}
static __device__ __forceinline__ float rsum32(float v){
  #pragma unroll
  for (int m=16;m>0;m>>=1) v += __shfl_xor(v,m,32);
  return v;
}
static __device__ __forceinline__ float rsum64(float v){
  #pragma unroll
  for (int m=32;m>0;m>>=1) v += __shfl_xor(v,m,64);
  return v;
}

// ---------------- weight conversion ----------------
__global__ __launch_bounds__(256) void cvt4_kernel(const float* __restrict__ src,
                                                   u16* __restrict__ dst, int n4){
  int i = blockIdx.x*256 + threadIdx.x;
  if (i >= n4) return;
  float4 v = *(const float4*)(src + (size_t)i*4);
  ushort4 o; o.x=f2bf(v.x); o.y=f2bf(v.y); o.z=f2bf(v.z); o.w=f2bf(v.w);
  *(ushort4*)(dst + (size_t)i*4) = o;
}
__global__ __launch_bounds__(256) void cvt_pad_kernel(const float* __restrict__ src,
                                                      u16* __restrict__ dst,
                                                      int rows, int K, int ldw){
  int i = blockIdx.x*256 + threadIdx.x;
  if (i >= rows*ldw) return;
  int r = i/ldw, k = i - r*ldw;
  dst[i] = (k < K) ? f2bf(src[(size_t)r*K + k]) : (u16)0;
}

// ---------------- LayerNorm over C=256 -> bf16 ----------------
__global__ __launch_bounds__(256) void ln_kernel(const float* __restrict__ in,
                                                 const float* __restrict__ w,
                                                 const float* __restrict__ bsh,
                                                 u16* __restrict__ out){
  int row = blockIdx.x, tid = threadIdx.x;
  float v = in[(size_t)row*C_+tid];
  float s = rsum64(v), q = rsum64(v*v);
  __shared__ float s1[4], s2[4];
  if ((tid&63)==0){ s1[tid>>6]=s; s2[tid>>6]=q; }
  __syncthreads();
  float ts=s1[0]+s1[1]+s1[2]+s1[3];
  float tq=s2[0]+s2[1]+s2[2]+s2[3];
  float m = ts*(1.0f/C_);
  float var = tq*(1.0f/C_)-m*m;
  float inv = rsqrtf(var+1e-5f);
  out[(size_t)row*C_+tid] = f2bf((v-m)*inv*w[tid]+bsh[tid]);
}

// ---------------- bf16-in GEMM, 64x64 tile, BK=32 (sync staging) ----------------
template<int ACT, int RES, int OUTBF>
__global__ __launch_bounds__(256) void gemm64b(const u16* __restrict__ A, int lda,
                                               const u16* __restrict__ W, int ldw,
                                               const float* __restrict__ bias,
                                               const float* __restrict__ res,
                                               void* __restrict__ outv,
                                               int M, int Nt, int K){
  constexpr int LDT = 40;
  __shared__ u16 As[64*LDT];
  __shared__ u16 Bs[64*LDT];
  int tid = threadIdx.x, lane = tid & 63;
  int wave = tid >> 6;
  int m0 = blockIdx.x*64, n0 = blockIdx.y*64;
  int wm = (wave>>1)*32, wn = (wave&1)*32;
  f32x4 acc[2][2];
  #pragma unroll
  for (int i=0;i<2;i++)
    #pragma unroll
    for (int j=0;j<2;j++) acc[i][j] = (f32x4){0.f,0.f,0.f,0.f};

  const int Kt = (K + 31) & ~31;
  const int l15 = lane & 15, quad = lane >> 4;
  int r  = tid >> 2;
  int c8 = (tid & 3) * 8;

  for (int k0=0; k0<Kt; k0+=32){
    int gk = k0 + c8;
    u16x8 av = (u16x8){0,0,0,0,0,0,0,0};
    if (m0 + r < M && gk + 8 <= lda)
      av = *(const u16x8*)(A + (size_t)(m0+r)*lda + gk);
    *(u16x8*)(&As[r*LDT + c8]) = av;
    u16x8 bv = (u16x8){0,0,0,0,0,0,0,0};
    if (n0 + r < Nt && gk + 8 <= ldw)
      bv = *(const u16x8*)(W + (size_t)(n0+r)*ldw + gk);
    *(u16x8*)(&Bs[r*LDT + c8]) = bv;
    __syncthreads();
    bf16x8 af[2], bfr[2];
    #pragma unroll
    for (int mi=0;mi<2;mi++)
      af[mi] = *(bf16x8*)(&As[(wm + mi*16 + l15)*LDT + quad*8]);
    #pragma unroll
    for (int nj=0;nj<2;nj++)
      bfr[nj] = *(bf16x8*)(&Bs[(wn + nj*16 + l15)*LDT + quad*8]);
    #pragma unroll
    for (int mi=0;mi<2;mi++)
      #pragma unroll
      for (int nj=0;nj<2;nj++)
        acc[mi][nj] = __builtin_amdgcn_mfma_f32_16x16x32_bf16(af[mi], bfr[nj], acc[mi][nj], 0,0,0);
    __syncthreads();
  }
  int rbase = quad*4;
  #pragma unroll
  for (int nj=0;nj<2;nj++){
    int gc = n0 + wn + nj*16 + l15;
    if (gc >= Nt) continue;
    float bv = bias[gc];
    #pragma unroll
    for (int mi=0;mi<2;mi++){
      #pragma unroll
      for (int reg=0;reg<4;reg++){
        int gr = m0 + wm + mi*16 + rbase + reg;
        if (gr >= M) continue;
        float v = acc[mi][nj][reg] + bv;
        if (ACT==1) v = gelu_f(v);
        if (RES)   v += res[(size_t)gr*Nt + gc];
        if (OUTBF) ((u16*)outv)[(size_t)gr*Nt + gc] = f2bf(v);
        else       ((float*)outv)[(size_t)gr*Nt + gc] = v;
      }
    }
  }
}

// ---------------- async bf16 GEMM, 128x128 tile, BK=32 (fc1; bf16 out, ldo-padded) ----
__global__ __launch_bounds__(256) void gemm128a(const u16* __restrict__ A, int lda,
                                                const u16* __restrict__ W, int ldw,
                                                const float* __restrict__ bias,
                                                u16* __restrict__ out,
                                                int M, int Nt, int K, int ldo){
  __shared__ u16 smem[8704];
  u16* As = smem;
  u16* Bs = smem + 4096;
  int tid = threadIdx.x, lane = tid & 63, wave = tid >> 6;
  int m0 = blockIdx.x*128, n0 = blockIdx.y*128;
  int wm = (wave>>1)*64, wn = (wave&1)*64;
  int l15 = lane & 15, quad = lane >> 4;
  f32x4 acc[4][4];
  #pragma unroll
  for (int i=0;i<4;i++)
    #pragma unroll
    for (int j=0;j<4;j++) acc[i][j] = (f32x4){0.f,0.f,0.f,0.f};

  const int Kt = (K + 31) & ~31;
  const u16* ga = A + (size_t)(m0 + lane)*lda + wave*8;
  const u16* gb = W + (size_t)(n0 + lane)*ldw + wave*8;
  u16* la = As + wave*1024;
  u16* lb = Bs + wave*1024;

  for (int k0=0; k0<Kt; k0+=32){
    gld_lds16(ga + k0,            la);
    gld_lds16(ga + 64*lda + k0,   la + 512);
    gld_lds16(gb + k0,            lb);
    gld_lds16(gb + 64*ldw + k0,   lb + 512);
    __syncthreads();
    bf16x8 af[4], bfr[4];
    #pragma unroll
    for (int mi=0;mi<4;mi++)
      af[mi] = *(bf16x8*)(&As[quad*1024 + (wm + mi*16 + l15)*8]);
    #pragma unroll
    for (int nj=0;nj<4;nj++)
      bfr[nj] = *(bf16x8*)(&Bs[quad*1024 + (wn + nj*16 + l15)*8]);
    #pragma unroll
    for (int mi=0;mi<4;mi++)
      #pragma unroll
      for (int nj=0;nj<4;nj++)
        acc[mi][nj] = __builtin_amdgcn_mfma_f32_16x16x32_bf16(af[mi], bfr[nj], acc[mi][nj], 0,0,0);
    __syncthreads();
  }

  u16* Cs = smem;
  #pragma unroll
  for (int p=0;p<2;p++){
    if (wm == p*64){
      #pragma unroll
      for (int nj=0;nj<4;nj++){
        int cc = wn + nj*16 + l15;
        int gc = n0 + cc;
        float bv = (gc < Nt) ? bias[gc] : 0.f;
        #pragma unroll
        for (int mi=0;mi<4;mi++)
          #pragma unroll
          for (int reg=0;reg<4;reg++){
            int rr = mi*16 + quad*4 + reg;
            Cs[rr*136 + cc] = f2bf(acc[mi][nj][reg] + bv);
          }
      }
    }
    __syncthreads();
    int r = tid >> 2, cb = (tid & 3)*32;
    int gr = m0 + p*64 + r;
    if (gr < M){
      u16* op = out + (size_t)gr*ldo + n0;
      #pragma unroll
      for (int k=0;k<4;k++){
        int c0 = cb + k*8;
        if (n0 + c0 + 8 <= ldo)
          *(u16x8*)(op + c0) = *(u16x8*)&Cs[r*136 + c0];
      }
    }
    __syncthreads();
  }
}

// ---------------- q post (bf16 in place) ----------------
__global__ __launch_bounds__(256) void qpost_kernel(u16* __restrict__ q,
                                                    const float* __restrict__ qe,
                                                    const float* __restrict__ temp,
                                                    const float* __restrict__ sls,
                                                    u16* __restrict__ qs_out){
  int row = blockIdx.x, tid = threadIdx.x, h = tid>>5;
  size_t idx = (size_t)row*C_ + tid;
  float v = b2f(q[idx]);
  float ss = rsum32(v*v);
  float qn = v / fmaxf(sqrtf(ss), 1e-12f);
  q[idx] = f2bf(qn);
  float t  = temp[h];
  float sp = log1pf(expf(t));
  float scale = sp * sls[0];
  qs_out[idx] = f2bf((qn + qe[tid])*scale);
}

// ---------------- k l2norm in place (bf16, stride 512) ----------------
__global__ __launch_bounds__(256) void knorm_kernel(u16* __restrict__ kv){
  int row = blockIdx.x, tid = threadIdx.x;
  size_t idx = (size_t)row*512 + tid;
  float v = b2f(kv[idx]);
  float ss = rsum32(v*v);
  kv[idx] = f2bf(v / fmaxf(sqrtf(ss), 1e-12f));
}

// ---------------- 8x8 avg pool + LN (bf16 -> bf16) ----------------
__global__ __launch_bounds__(256) void pool_ln_kernel(const u16* __restrict__ xsr,
                                                      const float* __restrict__ w,
                                                      const float* __restrict__ bsh,
                                                      u16* __restrict__ out){
  int blk = blockIdx.x; int b = blk/PL_; int p = blk%PL_;
  int py = p/7, px = p%7;
  int o = threadIdx.x;
  float s = 0.f;
  for (int iy=0;iy<8;iy++){
    const u16* rowp = xsr + ((size_t)(b*N_ + (py*8+iy)*WW + px*8))*C_ + o;
    #pragma unroll
    for (int ix=0;ix<8;ix++) s += b2f(rowp[(size_t)ix*C_]);
  }
  s *= (1.0f/64.0f);
  float su = rsum64(s), sq = rsum64(s*s);
  __shared__ float s1[4], s2[4];
  if ((o&63)==0){ s1[o>>6]=su; s2[o>>6]=sq; }
  __syncthreads();
  float ts=s1[0]+s1[1]+s1[2]+s1[3];
  float tq=s2[0]+s2[1]+s2[2]+s2[3];
  float m = ts*(1.0f/256.0f), var = tq*(1.0f/256.0f)-m*m;
  float inv = rsqrtf(var+1e-5f);
  out[(size_t)blk*C_+o] = f2bf((s-m)*inv*w[o]+bsh[o]);
}

// ---------------- CPB MLP (f32) ----------------
__global__ __launch_bounds__(256) void cpb_kernel(const float* __restrict__ rct,
                                                  const float* __restrict__ w1,
                                                  const float* __restrict__ b1,
                                                  const float* __restrict__ w2,
                                                  const float* __restrict__ b2v,
                                                  float* __restrict__ cpb){
  __shared__ float r[512];
  int t = blockIdx.x, tid = threadIdx.x;
  float c0 = rct[t*2], c1 = rct[t*2+1];
  for (int j=tid;j<512;j+=256){
    float v = c0*w1[j*2] + c1*w1[j*2+1] + b1[j];
    r[j] = fmaxf(v, 0.f);
  }
  __syncthreads();
  int h = tid>>5, lane = tid&31;
  float s = 0.f;
  for (int j=lane;j<512;j+=32) s += r[j]*w2[h*512+j];
  s = rsum32(s);
  if (lane==0) cpb[t*8+h] = s + b2v[h];
}

// ---------------- local attention logits, token-major attn [b][n][h][58] ----------------
// thread per (n,h): 32 rows/block, no shuffles, 9 contiguous f32 writes
__global__ __launch_bounds__(256) void attn_local_v3(const u16* __restrict__ qs,
                                                     const u16* __restrict__ kv,
                                                     const float* __restrict__ rpb,
                                                     float* __restrict__ attn){
  int t = threadIdx.x;
  int row = blockIdx.x*32 + (t>>3);
  int h = t & 7;
  int b = row / N_, n = row - b*N_;
  int y = n / WW, x = n - y*WW;
  const u16* qp = qs + (size_t)row*C_ + h*32;
  float q[32];
  #pragma unroll
  for (int j=0;j<4;j++){
    u16x8 v = *(const u16x8*)(qp + j*8);
    #pragma unroll
    for (int e=0;e<8;e++) q[j*8+e] = b2f(v[e]);
  }
  float* arow = attn + ((size_t)row*8 + h)*58;
  #pragma unroll
  for (int l=0;l<9;l++){
    int yy = y + l/3 - 1, xx = x + l%3 - 1;
    float s = 0.f;
    if (yy>=0 && yy<HH && xx>=0 && xx<WW){
      const u16* kp = kv + ((size_t)(b*N_ + yy*WW + xx))*512 + h*32;
      #pragma unroll
      for (int j=0;j<4;j++){
        u16x8 kw = *(const u16x8*)(kp + j*8);
        #pragma unroll
        for (int e=0;e<8;e++) s = fmaf(q[j*8+e], b2f(kw[e]), s);
      }
    }
    arow[l] = s + rpb[h*9+l];
  }
}

// ---------------- pooled attention logits via MFMA, token-major epilogue ----------------
__global__ __launch_bounds__(256) void attn_pool_mfma(const u16* __restrict__ qs,
                                                      const u16* __restrict__ kvp2,
                                                      const float* __restrict__ cpb,
                                                      const int* __restrict__ ridx,
                                                      float* __restrict__ attn){
  int tid = threadIdx.x, lane = tid & 63, wave = tid >> 6;
  int l15 = lane & 15, quad = lane >> 4;
  int bh = blockIdx.y, b = bh >> 3, h = bh & 7;
  int n0 = (blockIdx.x*4 + wave)*16;
  bf16x8 af = *(const bf16x8*)(qs + ((size_t)(b*N_ + n0 + l15)*C_ + h*32 + quad*8));
  f32x4 acc[4];
  #pragma unroll
  for (int nj=0;nj<4;nj++){
    int p = nj*16 + l15;
    bf16x8 bfr = (bf16x8){0,0,0,0,0,0,0,0};
    if (p < PL_)
      bfr = *(const bf16x8*)(kvp2 + ((size_t)(b*PL_ + p)*512 + h*32 + quad*8));
    f32x4 z = (f32x4){0.f,0.f,0.f,0.f};
    acc[nj] = __builtin_amdgcn_mfma_f32_16x16x32_bf16(af, bfr, z, 0,0,0);
  }
  #pragma unroll
  for (int nj=0;nj<4;nj++){
    int p = nj*16 + l15;
    if (p >= PL_) continue;
    #pragma unroll
    for (int reg=0;reg<4;reg++){
      int n = n0 + quad*4 + reg;
      float bias = cpb[ridx[(size_t)n*PL_ + p]*8 + h];
      attn[((size_t)(b*N_ + n)*8 + h)*58 + 9 + p] = acc[nj][reg] + bias;
    }
  }
}

// ---------------- builders ----------------
__global__ __launch_bounds__(256) void build_w72(const float* __restrict__ lt, u16* __restrict__ w72){
  int r = blockIdx.x, c = threadIdx.x;
  int h = r/9, l = r - h*9;
  w72[(size_t)r*256 + c] = ((c>>5) == h) ? f2bf(lt[((size_t)(h*32 + (c&31)))*9 + l]) : (u16)0;
}
__global__ __launch_bounds__(256) void build_dwwT(const float* __restrict__ dww, float* __restrict__ dwwT){
  int l = blockIdx.x;
  for (int f=threadIdx.x; f<684; f+=256)
    dwwT[(size_t)l*684 + f] = (f < HF_) ? dww[(size_t)f*9 + l] : 0.f;
}

// ---------------- fused softmax + x_local + x_pool -> out (bf16) ----------------
// one wave per token: stage 464 logits, softmax per head, add qlt, 4-ch vector gathers
__global__ __launch_bounds__(256) void xout_v3(const float* __restrict__ qlt,
                                               const float* __restrict__ attn,
                                               const u16* __restrict__ kv,
                                               const u16* __restrict__ kvp2,
                                               u16* __restrict__ out){
  __shared__ float coef[4][472];
  __shared__ float smx[4][8], sinv[4][8];
  int t = threadIdx.x, w = t>>6, l = t&63;
  int row = blockIdx.x*4 + w;
  int b = row / N_, n = row - b*N_;
  int y = n / WW, x = n - y*WW;
  const float* arow = attn + (size_t)row*464;
  for (int i=l; i<464; i+=64) coef[w][i] = arow[i];
  __syncthreads();
  if (l < 8){
    const float* c = &coef[w][l*58];
    float mx = -1e30f;
    for (int j=0;j<58;j++) mx = fmaxf(mx, c[j]);
    float s = 0.f;
    for (int j=0;j<58;j++) s += expf(c[j]-mx);
    smx[w][l] = mx; sinv[w][l] = 1.f/s;
  }
  __syncthreads();
  #pragma unroll
  for (int h2=0; h2<8; h2++){
    if (l < 58){
      float v = expf(coef[w][h2*58+l] - smx[w][h2]) * sinv[w][h2];
      if (l < 9) v += qlt[(size_t)row*72 + h2*9 + l];
      coef[w][h2*58+l] = v;
    }
  }
  __syncthreads();
  int c = l*4, h = l>>3;
  const float* ch = &coef[w][h*58];
  float a0=0.f, a1=0.f, a2=0.f, a3=0.f;
  #pragma unroll
  for (int lw=0; lw<9; lw++){
    int yy = y + lw/3 - 1, xx = x + lw%3 - 1;
    if (yy>=0 && yy<HH && xx>=0 && xx<WW){
      ushort4 vv = *(const ushort4*)(kv + ((size_t)(b*N_ + yy*WW + xx))*512 + 256 + c);
      float cf = ch[lw];
      a0 = fmaf(cf, b2f(vv.x), a0);
      a1 = fmaf(cf, b2f(vv.y), a1);
      a2 = fmaf(cf, b2f(vv.z), a2);
      a3 = fmaf(cf, b2f(vv.w), a3);
    }
  }
  const u16* pb = kvp2 + (size_t)b*PL_*512 + 256 + c;
  #pragma unroll 7
  for (int p=0;p<49;p++){
    ushort4 vv = *(const ushort4*)(pb + (size_t)p*512);
    float cf = ch[9+p];
    a0 = fmaf(cf, b2f(vv.x), a0);
    a1 = fmaf(cf, b2f(vv.y), a1);
    a2 = fmaf(cf, b2f(vv.z), a2);
    a3 = fmaf(cf, b2f(vv.w), a3);
  }
  ushort4 o; o.x=f2bf(a0); o.y=f2bf(a1); o.z=f2bf(a2); o.w=f2bf(a3);
  *(ushort4*)(out + (size_t)row*C_ + c) = o;
}

// ---------------- depthwise 3x3 + gelu gate, XCD-confined per batch ----------------
__global__ __launch_bounds__(256) void dwconv_v3(const u16* __restrict__ hsrc,
                                                 const float* __restrict__ dwwT,
                                                 const float* __restrict__ dwb,
                                                 u16* __restrict__ hg){
  int b = blockIdx.x;
  int idx = blockIdx.y*256 + threadIdx.x;
  if (idx >= N_*171) return;
  int n = idx/171, g = idx - n*171;
  int pix = b*N_ + n;
  int y = n / WW, x = n - y*WW;
  int f = g*4;
  const u16* hb = hsrc + (size_t)b*N_*HBLD;
  if (g < 170){
    float4 s = *(const float4*)(dwb + f);
    #pragma unroll
    for (int l=0;l<9;l++){
      int yy = y + l/3 - 1, xx = x + l%3 - 1;
      if (yy>=0 && yy<HH && xx>=0 && xx<WW){
        ushort4 hv = *(const ushort4*)(hb + (size_t)(yy*WW+xx)*HBLD + f);
        float4 wv = *(const float4*)(dwwT + (size_t)l*684 + f);
        s.x = fmaf(b2f(hv.x), wv.x, s.x);
        s.y = fmaf(b2f(hv.y), wv.y, s.y);
        s.z = fmaf(b2f(hv.z), wv.z, s.z);
        s.w = fmaf(b2f(hv.w), wv.w, s.w);
      }
    }
    const u16* vp = hsrc + (size_t)pix*HBLD + HF_ + f;
    ushort2 v0 = *(const ushort2*)vp, v1 = *(const ushort2*)(vp+2);
    ushort4 o;
    o.x = f2bf(gelu_f(s.x)*b2f(v0.x)); o.y = f2bf(gelu_f(s.y)*b2f(v0.y));
    o.z = f2bf(gelu_f(s.z)*b2f(v1.x)); o.w = f2bf(gelu_f(s.w)*b2f(v1.y));
    *(ushort4*)(hg + (size_t)pix*HGLD + f) = o;
  } else {
    float r[2];
    #pragma unroll
    for (int c=0;c<2;c++){
      int ff = 680 + c;
      float s = dwb[ff];
      #pragma unroll
      for (int l=0;l<9;l++){
        int yy = y + l/3 - 1, xx = x + l%3 - 1;
        if (yy>=0 && yy<HH && xx>=0 && xx<WW)
          s += b2f(hb[(size_t)(yy*WW+xx)*HBLD + ff]) * dwwT[(size_t)l*684 + ff];
      }
      r[c] = gelu_f(s) * b2f(hsrc[(size_t)pix*HBLD + HF_ + ff]);
    }
    u16* hp = hg + (size_t)pix*HGLD;
    ushort4 o1; o1.x = f2bf(r[0]); o1.y = f2bf(r[1]); o1.z = 0; o1.w = 0;
    *(ushort4*)(hp + 680) = o1;
    ushort4 z4 = {0,0,0,0};
    *(ushort4*)(hp + 684) = z4;
    *(ushort4*)(hp + 688) = z4;
    *(ushort4*)(hp + 692) = z4;
    *(ushort4*)(hp + 696) = z4;
    *(ushort4*)(hp + 700) = z4;
  }
}

extern "C" void kernel_launch(void* const* d_in, const int* in_sizes, int n_in,
                              void* d_out, int out_size, void* d_ws, size_t ws_size,
                              hipStream_t stream) {
  const float* x    = (const float*)d_in[0];
  const float* rct  = (const float*)d_in[1];
  const float* sls  = (const float*)d_in[2];
  const float* n1w  = (const float*)d_in[3];
  const float* n1b  = (const float*)d_in[4];
  const float* q_w  = (const float*)d_in[5];
  const float* q_b  = (const float*)d_in[6];
  const float* kv_w = (const float*)d_in[7];
  const float* kv_b = (const float*)d_in[8];
  const float* temp = (const float*)d_in[9];
  const float* qe   = (const float*)d_in[10];
  const float* rpb  = (const float*)d_in[11];
  const float* lt   = (const float*)d_in[12];
  const float* lb   = (const float*)d_in[13];
  const float* sr_w = (const float*)d_in[14];
  const float* sr_b = (const float*)d_in[15];
  const float* npw  = (const float*)d_in[16];
  const float* npb  = (const float*)d_in[17];
  const float* c1w  = (const float*)d_in[18];
  const float* c1b  = (const float*)d_in[19];
  const float* c2w  = (const float*)d_in[20];
  const float* c2b  = (const float*)d_in[21];
  const float* pw   = (const float*)d_in[22];
  const float* pb   = (const float*)d_in[23];
  const float* n2w  = (const float*)d_in[24];
  const float* n2b  = (const float*)d_in[25];
  const float* f1w  = (const float*)d_in[26];
  const float* f1b  = (const float*)d_in[27];
  const float* dww  = (const float*)d_in[28];
  const float* dwb  = (const float*)d_in[29];
  const float* f2w  = (const float*)d_in[30];
  const float* f2bb = (const float*)d_in[31];
  const int*  ridx  = (const int*)d_in[32];
  float* outp = (float*)d_out;

  char* ws = (char*)d_ws;
  constexpr size_t SZ_BNC2 = (size_t)MROWS*C_*2;
  constexpr size_t SZ_KV2  = (size_t)MROWS*512*2;
  constexpr size_t SZ_ATTN = (size_t)MROWS*464*4;       // 46,563,328 (token-major)
  size_t o_xn   = 0;
  size_t o_qn   = o_xn   + SZ_BNC2;
  size_t o_qs   = o_qn   + SZ_BNC2;
  size_t o_kv   = o_qs   + SZ_BNC2;
  size_t o_attn = o_kv   + SZ_KV2;
  size_t o_xsr  = o_attn + SZ_ATTN;
  size_t o_xpln = o_xsr  + SZ_BNC2;
  size_t o_kvp2 = o_xpln + (size_t)B_*PL_*C_*2;
  size_t o_cpb  = o_kvp2 + (size_t)B_*PL_*512*2;
  size_t o_outb = o_cpb  + (size_t)1024*8*4;
  size_t o_x2   = o_outb + SZ_BNC2;
  size_t o_qlt  = o_x2   + (size_t)MROWS*C_*4;
  size_t o_wq   = o_qlt  + (size_t)MROWS*72*4;
  size_t o_wkv  = o_wq   + (size_t)65536*2;
  size_t o_wsr  = o_wkv  + (size_t)131072*2;
  size_t o_wp   = o_wsr  + (size_t)65536*2;
  size_t o_wf1  = o_wp   + (size_t)65536*2;
  size_t o_wf2  = o_wf1  + (size_t)349184*2;
  size_t o_w72  = o_wf2  + (size_t)256*F2LD*2;
  size_t o_dwwT = o_w72  + (size_t)72*256*2;
  size_t o_h    = o_kv;   // hbuf 68.6MB over kv+attn (dead after xout) — dead regions by step 17
  size_t o_hg   = 0;      // hg 35.3MB over xn+qn+qs (dead by 18)

  u16*   xn   = (u16*)(ws + o_xn);
  u16*   qbuf = (u16*)(ws + o_qn);
  u16*   qsc  = (u16*)(ws + o_qs);
  u16*   kv   = (u16*)(ws + o_kv);
  float* attn = (float*)(ws + o_attn);
  u16*   xsr  = (u16*)(ws + o_xsr);
  u16*   xpln = (u16*)(ws + o_xpln);
  u16*   kvp2 = (u16*)(ws + o_kvp2);
  float* cpb  = (float*)(ws + o_cpb);
  u16*   outb = (u16*)(ws + o_outb);
  float* x2   = (float*)(ws + o_x2);
  float* qlt  = (float*)(ws + o_qlt);
  u16*   wq   = (u16*)(ws + o_wq);
  u16*   wkv  = (u16*)(ws + o_wkv);
  u16*   wsr  = (u16*)(ws + o_wsr);
  u16*   wp   = (u16*)(ws + o_wp);
  u16*   wf1  = (u16*)(ws + o_wf1);
  u16*   wf2  = (u16*)(ws + o_wf2);
  u16*   w72  = (u16*)(ws + o_w72);
  float* dwwT = (float*)(ws + o_dwwT);
  u16*   hbuf = (u16*)(ws + o_h);
  u16*   hg   = (u16*)(ws + o_hg);

  // 0. weight conversions (bf16 copies)
  cvt4_kernel<<<(65536/4+255)/256, 256, 0, stream>>>(q_w,  wq,  65536/4);
  cvt4_kernel<<<(131072/4+255)/256,256, 0, stream>>>(kv_w, wkv, 131072/4);
  cvt4_kernel<<<(65536/4+255)/256, 256, 0, stream>>>(sr_w, wsr, 65536/4);
  cvt4_kernel<<<(65536/4+255)/256, 256, 0, stream>>>(pw,   wp,  65536/4);
  cvt4_kernel<<<(349184/4+255)/256,256, 0, stream>>>(f1w,  wf1, 349184/4);
  cvt_pad_kernel<<<(256*F2LD+255)/256, 256, 0, stream>>>(f2w, wf2, 256, HF_, F2LD);
  build_w72<<<72, 256, 0, stream>>>(lt, w72);
  build_dwwT<<<9, 256, 0, stream>>>(dww, dwwT);

  // 1. xn = LN(x) -> bf16
  ln_kernel<<<MROWS, 256, 0, stream>>>(x, n1w, n1b, xn);
  // 2. q = xn @ q_w^T + q_b -> bf16
  gemm64b<0,0,1><<<dim3(392,4), 256, 0, stream>>>(xn, C_, wq, C_, q_b, nullptr, qbuf, MROWS, 256, 256);
  // 3. kv = xn @ kv_w^T + kv_b -> bf16
  gemm64b<0,0,1><<<dim3(392,8), 256, 0, stream>>>(xn, C_, wkv, C_, kv_b, nullptr, kv, MROWS, 512, 256);
  // 4. q_norm (in place) + q_scaled
  qpost_kernel<<<MROWS, 256, 0, stream>>>(qbuf, qe, temp, sls, qsc);
  // 5. k l2norm in place
  knorm_kernel<<<MROWS, 256, 0, stream>>>(kv);
  // 6. x_sr = gelu(xn @ sr_w^T + sr_b) -> bf16
  gemm64b<1,0,1><<<dim3(392,4), 256, 0, stream>>>(xn, C_, wsr, C_, sr_b, nullptr, xsr, MROWS, 256, 256);
  // 7. 8x8 avg pool + LN(normp) -> bf16
  pool_ln_kernel<<<B_*PL_, 256, 0, stream>>>(xsr, npw, npb, xpln);
  // 8. kvp2 = xpln @ kv_w^T + kv_b -> bf16
  gemm64b<0,0,1><<<dim3(7,8), 256, 0, stream>>>(xpln, C_, wkv, C_, kv_b, nullptr, kvp2, B_*PL_, 512, 256);
  // 9. k_pool l2norm in place
  knorm_kernel<<<B_*PL_, 256, 0, stream>>>(kvp2);
  // 10. CPB MLP
  cpb_kernel<<<1024, 256, 0, stream>>>(rct, c1w, c1b, c2w, c2b, cpb);
  // 10b. qlt = qn @ w72^T + lb -> f32
  gemm64b<0,0,0><<<dim3(392,2), 256, 0, stream>>>(qbuf, C_, w72, C_, lb, nullptr, qlt, MROWS, 72, 256);
  // 11. local attention logits (token-major)
  attn_local_v3<<<MROWS/32, 256, 0, stream>>>(qsc, kv, rpb, attn);
  // 12. pooled attention logits (MFMA, token-major)
  attn_pool_mfma<<<dim3(49,64), 256, 0, stream>>>(qsc, kvp2, cpb, ridx, attn);
  // 13+14. fused softmax + x_local + x_pool -> outb bf16
  xout_v3<<<MROWS/4, 256, 0, stream>>>(qlt, attn, kv, kvp2, outb);
  // 15. x2 = x + outb @ proj_w^T + proj_b -> f32
  gemm64b<0,1,0><<<dim3(392,4), 256, 0, stream>>>(outb, C_, wp, C_, pb, x, x2, MROWS, 256, 256);
  // 16. xn2 = LN(x2) -> bf16 (reuses xn)
  ln_kernel<<<MROWS, 256, 0, stream>>>(x2, n2w, n2b, xn);
  // 17. h = xn2 @ fc1_w^T + fc1_b -> bf16 (ldo=HBLD, async 128-tile)
  gemm128a<<<dim3(196,11), 256, 0, stream>>>(xn, C_, wf1, C_, f1b, hbuf, MROWS, 1364, 256, HBLD);
  // 18. hg = gelu(dwconv(h1)+dwb) * v -> bf16 (XCD-confined grid)
  dwconv_v3<<<dim3(8, (N_*171+255)/256), 256, 0, stream>>>(hbuf, dwwT, dwb, hg);
  // 19. out = x2 + hg @ fc2_w^T + fc2_b -> f32
  gemm64b<0,1,0><<<dim3(392,4), 256, 0, stream>>>(hg, HGLD, wf2, F2LD, f2bb, x2, outp, MROWS, 256, HF_);
}

// Round 10
// 601.076 us; speedup vs baseline: 1.2563x; 1.0565x over previous
//
#include <hip/hip_runtime.h>
#include <math.h>

#define B_   8
#define N_   3136
#define C_   256
#define NH_  8
#define HD_  32
#define LL_  9
#define PL_  49
#define HF_  682
#define HH   56
#define WW   56
#define MROWS (B_*N_)   // 25088
#define HGLD  704       // hg row stride (bf16); cols 682..703 zeroed (Kt for K=682)
#define F2LD  704       // fc2 weight ld (bf16), zero-padded
#define HBLD  1368      // hbuf row stride (bf16); 16B-aligned rows

typedef short          bf16x8 __attribute__((ext_vector_type(8)));
typedef unsigned short u16x8  __attribute__((ext_vector_type(8)));
typedef float          f32x4  __attribute__((ext_vector_type(4)));
typedef unsigned short u16;

static __device__ __forceinline__ float gelu_f(float x){ return 0.5f*x*(1.0f+erff(x*0.70710678118654752f)); }
static __device__ __forceinline__ u16 f2bf(float f){
  union { float f; unsigned u; } x; x.f = f;
  unsigned r = (x.u + 0x7FFFu + ((x.u >> 16) & 1u)) >> 16;
  return (u16)r;
}
static __device__ __forceinline__ float b2f(u16 u){
  union { unsigned u; float f; } x; x.u = ((unsigned)u) << 16;
  return x.f;
}
// async global->LDS, 16B per lane; lds dest = wave-uniform base + lane*16
static __device__ __forceinline__ void gld_lds16(const u16* g, u16* l){
  __builtin_amdgcn_global_load_lds((const __attribute__((address_space(1))) void*)g,
                                   (__attribute__((address_space(3))) void*)l, 16, 0, 0);
}
static __device__ __forceinline__ float rsum32(float v){
  #pragma unroll
  for (int m=16;m>0;m>>=1) v += __shfl_xor(v,m,32);
  return v;
}
static __device__ __forceinline__ float rsum64(float v){
  #pragma unroll
  for (int m=32;m>0;m>>=1) v += __shfl_xor(v,m,64);
  return v;
}

// ---------------- weight conversion ----------------
__global__ __launch_bounds__(256) void cvt4_kernel(const float* __restrict__ src,
                                                   u16* __restrict__ dst, int n4){
  int i = blockIdx.x*256 + threadIdx.x;
  if (i >= n4) return;
  float4 v = *(const float4*)(src + (size_t)i*4);
  ushort4 o; o.x=f2bf(v.x); o.y=f2bf(v.y); o.z=f2bf(v.z); o.w=f2bf(v.w);
  *(ushort4*)(dst + (size_t)i*4) = o;
}
__global__ __launch_bounds__(256) void cvt_pad_kernel(const float* __restrict__ src,
                                                      u16* __restrict__ dst,
                                                      int rows, int K, int ldw){
  int i = blockIdx.x*256 + threadIdx.x;
  if (i >= rows*ldw) return;
  int r = i/ldw, k = i - r*ldw;
  dst[i] = (k < K) ? f2bf(src[(size_t)r*K + k]) : (u16)0;
}

// ---------------- LayerNorm over C=256 -> bf16 ----------------
__global__ __launch_bounds__(256) void ln_kernel(const float* __restrict__ in,
                                                 const float* __restrict__ w,
                                                 const float* __restrict__ bsh,
                                                 u16* __restrict__ out){
  int row = blockIdx.x, tid = threadIdx.x;
  float v = in[(size_t)row*C_+tid];
  float s = rsum64(v), q = rsum64(v*v);
  __shared__ float s1[4], s2[4];
  if ((tid&63)==0){ s1[tid>>6]=s; s2[tid>>6]=q; }
  __syncthreads();
  float ts=s1[0]+s1[1]+s1[2]+s1[3];
  float tq=s2[0]+s2[1]+s2[2]+s2[3];
  float m = ts*(1.0f/C_);
  float var = tq*(1.0f/C_)-m*m;
  float inv = rsqrtf(var+1e-5f);
  out[(size_t)row*C_+tid] = f2bf((v-m)*inv*w[tid]+bsh[tid]);
}

// ---------------- bf16-in GEMM, 64x64 tile, BK=32 (sync staging) ----------------
template<int ACT, int RES, int OUTBF>
__global__ __launch_bounds__(256) void gemm64b(const u16* __restrict__ A, int lda,
                                               const u16* __restrict__ W, int ldw,
                                               const float* __restrict__ bias,
                                               const float* __restrict__ res,
                                               void* __restrict__ outv,
                                               int M, int Nt, int K){
  constexpr int LDT = 40;
  __shared__ u16 As[64*LDT];
  __shared__ u16 Bs[64*LDT];
  int tid = threadIdx.x, lane = tid & 63;
  int wave = tid >> 6;
  int m0 = blockIdx.x*64, n0 = blockIdx.y*64;
  int wm = (wave>>1)*32, wn = (wave&1)*32;
  f32x4 acc[2][2];
  #pragma unroll
  for (int i=0;i<2;i++)
    #pragma unroll
    for (int j=0;j<2;j++) acc[i][j] = (f32x4){0.f,0.f,0.f,0.f};

  const int Kt = (K + 31) & ~31;
  const int l15 = lane & 15, quad = lane >> 4;
  int r  = tid >> 2;
  int c8 = (tid & 3) * 8;

  for (int k0=0; k0<Kt; k0+=32){
    int gk = k0 + c8;
    u16x8 av = (u16x8){0,0,0,0,0,0,0,0};
    if (m0 + r < M && gk + 8 <= lda)
      av = *(const u16x8*)(A + (size_t)(m0+r)*lda + gk);
    *(u16x8*)(&As[r*LDT + c8]) = av;
    u16x8 bv = (u16x8){0,0,0,0,0,0,0,0};
    if (n0 + r < Nt && gk + 8 <= ldw)
      bv = *(const u16x8*)(W + (size_t)(n0+r)*ldw + gk);
    *(u16x8*)(&Bs[r*LDT + c8]) = bv;
    __syncthreads();
    bf16x8 af[2], bfr[2];
    #pragma unroll
    for (int mi=0;mi<2;mi++)
      af[mi] = *(bf16x8*)(&As[(wm + mi*16 + l15)*LDT + quad*8]);
    #pragma unroll
    for (int nj=0;nj<2;nj++)
      bfr[nj] = *(bf16x8*)(&Bs[(wn + nj*16 + l15)*LDT + quad*8]);
    #pragma unroll
    for (int mi=0;mi<2;mi++)
      #pragma unroll
      for (int nj=0;nj<2;nj++)
        acc[mi][nj] = __builtin_amdgcn_mfma_f32_16x16x32_bf16(af[mi], bfr[nj], acc[mi][nj], 0,0,0);
    __syncthreads();
  }
  int rbase = quad*4;
  #pragma unroll
  for (int nj=0;nj<2;nj++){
    int gc = n0 + wn + nj*16 + l15;
    if (gc >= Nt) continue;
    float bv = bias[gc];
    #pragma unroll
    for (int mi=0;mi<2;mi++){
      #pragma unroll
      for (int reg=0;reg<4;reg++){
        int gr = m0 + wm + mi*16 + rbase + reg;
        if (gr >= M) continue;
        float v = acc[mi][nj][reg] + bv;
        if (ACT==1) v = gelu_f(v);
        if (RES)   v += res[(size_t)gr*Nt + gc];
        if (OUTBF) ((u16*)outv)[(size_t)gr*Nt + gc] = f2bf(v);
        else       ((float*)outv)[(size_t)gr*Nt + gc] = v;
      }
    }
  }
}

// ---------------- async bf16 GEMM, 128x128 tile, BK=32 (fc1; bf16 out, ldo-padded) ----
__global__ __launch_bounds__(256) void gemm128a(const u16* __restrict__ A, int lda,
                                                const u16* __restrict__ W, int ldw,
                                                const float* __restrict__ bias,
                                                u16* __restrict__ out,
                                                int M, int Nt, int K, int ldo){
  __shared__ u16 smem[8704];
  u16* As = smem;
  u16* Bs = smem + 4096;
  int tid = threadIdx.x, lane = tid & 63, wave = tid >> 6;
  int m0 = blockIdx.x*128, n0 = blockIdx.y*128;
  int wm = (wave>>1)*64, wn = (wave&1)*64;
  int l15 = lane & 15, quad = lane >> 4;
  f32x4 acc[4][4];
  #pragma unroll
  for (int i=0;i<4;i++)
    #pragma unroll
    for (int j=0;j<4;j++) acc[i][j] = (f32x4){0.f,0.f,0.f,0.f};

  const int Kt = (K + 31) & ~31;
  const u16* ga = A + (size_t)(m0 + lane)*lda + wave*8;
  const u16* gb = W + (size_t)(n0 + lane)*ldw + wave*8;
  u16* la = As + wave*1024;
  u16* lb = Bs + wave*1024;

  for (int k0=0; k0<Kt; k0+=32){
    gld_lds16(ga + k0,            la);
    gld_lds16(ga + 64*lda + k0,   la + 512);
    gld_lds16(gb + k0,            lb);
    gld_lds16(gb + 64*ldw + k0,   lb + 512);
    __syncthreads();
    bf16x8 af[4], bfr[4];
    #pragma unroll
    for (int mi=0;mi<4;mi++)
      af[mi] = *(bf16x8*)(&As[quad*1024 + (wm + mi*16 + l15)*8]);
    #pragma unroll
    for (int nj=0;nj<4;nj++)
      bfr[nj] = *(bf16x8*)(&Bs[quad*1024 + (wn + nj*16 + l15)*8]);
    #pragma unroll
    for (int mi=0;mi<4;mi++)
      #pragma unroll
      for (int nj=0;nj<4;nj++)
        acc[mi][nj] = __builtin_amdgcn_mfma_f32_16x16x32_bf16(af[mi], bfr[nj], acc[mi][nj], 0,0,0);
    __syncthreads();
  }

  u16* Cs = smem;
  #pragma unroll
  for (int p=0;p<2;p++){
    if (wm == p*64){
      #pragma unroll
      for (int nj=0;nj<4;nj++){
        int cc = wn + nj*16 + l15;
        int gc = n0 + cc;
        float bv = (gc < Nt) ? bias[gc] : 0.f;
        #pragma unroll
        for (int mi=0;mi<4;mi++)
          #pragma unroll
          for (int reg=0;reg<4;reg++){
            int rr = mi*16 + quad*4 + reg;
            Cs[rr*136 + cc] = f2bf(acc[mi][nj][reg] + bv);
          }
      }
    }
    __syncthreads();
    int r = tid >> 2, cb = (tid & 3)*32;
    int gr = m0 + p*64 + r;
    if (gr < M){
      u16* op = out + (size_t)gr*ldo + n0;
      #pragma unroll
      for (int k=0;k<4;k++){
        int c0 = cb + k*8;
        if (n0 + c0 + 8 <= ldo)
          *(u16x8*)(op + c0) = *(u16x8*)&Cs[r*136 + c0];
      }
    }
    __syncthreads();
  }
}

// ---------------- q post (bf16 in place) ----------------
__global__ __launch_bounds__(256) void qpost_kernel(u16* __restrict__ q,
                                                    const float* __restrict__ qe,
                                                    const float* __restrict__ temp,
                                                    const float* __restrict__ sls,
                                                    u16* __restrict__ qs_out){
  int row = blockIdx.x, tid = threadIdx.x, h = tid>>5;
  size_t idx = (size_t)row*C_ + tid;
  float v = b2f(q[idx]);
  float ss = rsum32(v*v);
  float qn = v / fmaxf(sqrtf(ss), 1e-12f);
  q[idx] = f2bf(qn);
  float t  = temp[h];
  float sp = log1pf(expf(t));
  float scale = sp * sls[0];
  qs_out[idx] = f2bf((qn + qe[tid])*scale);
}

// ---------------- k l2norm in place (bf16, stride 512) ----------------
__global__ __launch_bounds__(256) void knorm_kernel(u16* __restrict__ kv){
  int row = blockIdx.x, tid = threadIdx.x;
  size_t idx = (size_t)row*512 + tid;
  float v = b2f(kv[idx]);
  float ss = rsum32(v*v);
  kv[idx] = f2bf(v / fmaxf(sqrtf(ss), 1e-12f));
}

// ---------------- 8x8 avg pool + LN (bf16 -> bf16) ----------------
__global__ __launch_bounds__(256) void pool_ln_kernel(const u16* __restrict__ xsr,
                                                      const float* __restrict__ w,
                                                      const float* __restrict__ bsh,
                                                      u16* __restrict__ out){
  int blk = blockIdx.x; int b = blk/PL_; int p = blk%PL_;
  int py = p/7, px = p%7;
  int o = threadIdx.x;
  float s = 0.f;
  for (int iy=0;iy<8;iy++){
    const u16* rowp = xsr + ((size_t)(b*N_ + (py*8+iy)*WW + px*8))*C_ + o;
    #pragma unroll
    for (int ix=0;ix<8;ix++) s += b2f(rowp[(size_t)ix*C_]);
  }
  s *= (1.0f/64.0f);
  float su = rsum64(s), sq = rsum64(s*s);
  __shared__ float s1[4], s2[4];
  if ((o&63)==0){ s1[o>>6]=su; s2[o>>6]=sq; }
  __syncthreads();
  float ts=s1[0]+s1[1]+s1[2]+s1[3];
  float tq=s2[0]+s2[1]+s2[2]+s2[3];
  float m = ts*(1.0f/256.0f), var = tq*(1.0f/256.0f)-m*m;
  float inv = rsqrtf(var+1e-5f);
  out[(size_t)blk*C_+o] = f2bf((s-m)*inv*w[o]+bsh[o]);
}

// ---------------- CPB MLP (f32) ----------------
__global__ __launch_bounds__(256) void cpb_kernel(const float* __restrict__ rct,
                                                  const float* __restrict__ w1,
                                                  const float* __restrict__ b1,
                                                  const float* __restrict__ w2,
                                                  const float* __restrict__ b2v,
                                                  float* __restrict__ cpb){
  __shared__ float r[512];
  int t = blockIdx.x, tid = threadIdx.x;
  float c0 = rct[t*2], c1 = rct[t*2+1];
  for (int j=tid;j<512;j+=256){
    float v = c0*w1[j*2] + c1*w1[j*2+1] + b1[j];
    r[j] = fmaxf(v, 0.f);
  }
  __syncthreads();
  int h = tid>>5, lane = tid&31;
  float s = 0.f;
  for (int j=lane;j<512;j+=32) s += r[j]*w2[h*512+j];
  s = rsum32(s);
  if (lane==0) cpb[t*8+h] = s + b2v[h];
}

// ---------------- local attention logits, token-major attn [b][n][h][58] ----------------
__global__ __launch_bounds__(256) void attn_local_v3(const u16* __restrict__ qs,
                                                     const u16* __restrict__ kv,
                                                     const float* __restrict__ rpb,
                                                     float* __restrict__ attn){
  int t = threadIdx.x;
  int row = blockIdx.x*32 + (t>>3);
  int h = t & 7;
  int b = row / N_, n = row - b*N_;
  int y = n / WW, x = n - y*WW;
  const u16* qp = qs + (size_t)row*C_ + h*32;
  float q[32];
  #pragma unroll
  for (int j=0;j<4;j++){
    u16x8 v = *(const u16x8*)(qp + j*8);
    #pragma unroll
    for (int e=0;e<8;e++) q[j*8+e] = b2f(v[e]);
  }
  float* arow = attn + ((size_t)row*8 + h)*58;
  #pragma unroll
  for (int l=0;l<9;l++){
    int yy = y + l/3 - 1, xx = x + l%3 - 1;
    float s = 0.f;
    if (yy>=0 && yy<HH && xx>=0 && xx<WW){
      const u16* kp = kv + ((size_t)(b*N_ + yy*WW + xx))*512 + h*32;
      #pragma unroll
      for (int j=0;j<4;j++){
        u16x8 kw = *(const u16x8*)(kp + j*8);
        #pragma unroll
        for (int e=0;e<8;e++) s = fmaf(q[j*8+e], b2f(kw[e]), s);
      }
    }
    arow[l] = s + rpb[h*9+l];
  }
}

// ---------------- pooled attention logits via MFMA, token-major epilogue ----------------
__global__ __launch_bounds__(256) void attn_pool_mfma(const u16* __restrict__ qs,
                                                      const u16* __restrict__ kvp2,
                                                      const float* __restrict__ cpb,
                                                      const int* __restrict__ ridx,
                                                      float* __restrict__ attn){
  int tid = threadIdx.x, lane = tid & 63, wave = tid >> 6;
  int l15 = lane & 15, quad = lane >> 4;
  int bh = blockIdx.y, b = bh >> 3, h = bh & 7;
  int n0 = (blockIdx.x*4 + wave)*16;
  bf16x8 af = *(const bf16x8*)(qs + ((size_t)(b*N_ + n0 + l15)*C_ + h*32 + quad*8));
  f32x4 acc[4];
  #pragma unroll
  for (int nj=0;nj<4;nj++){
    int p = nj*16 + l15;
    bf16x8 bfr = (bf16x8){0,0,0,0,0,0,0,0};
    if (p < PL_)
      bfr = *(const bf16x8*)(kvp2 + ((size_t)(b*PL_ + p)*512 + h*32 + quad*8));
    f32x4 z = (f32x4){0.f,0.f,0.f,0.f};
    acc[nj] = __builtin_amdgcn_mfma_f32_16x16x32_bf16(af, bfr, z, 0,0,0);
  }
  #pragma unroll
  for (int nj=0;nj<4;nj++){
    int p = nj*16 + l15;
    if (p >= PL_) continue;
    #pragma unroll
    for (int reg=0;reg<4;reg++){
      int n = n0 + quad*4 + reg;
      float bias = cpb[ridx[(size_t)n*PL_ + p]*8 + h];
      attn[((size_t)(b*N_ + n)*8 + h)*58 + 9 + p] = acc[nj][reg] + bias;
    }
  }
}

// ---------------- builders ----------------
__global__ __launch_bounds__(256) void build_w72(const float* __restrict__ lt, u16* __restrict__ w72){
  int r = blockIdx.x, c = threadIdx.x;
  int h = r/9, l = r - h*9;
  w72[(size_t)r*256 + c] = ((c>>5) == h) ? f2bf(lt[((size_t)(h*32 + (c&31)))*9 + l]) : (u16)0;
}
__global__ __launch_bounds__(256) void build_dwwT(const float* __restrict__ dww, float* __restrict__ dwwT){
  int l = blockIdx.x;
  for (int f=threadIdx.x; f<684; f+=256)
    dwwT[(size_t)l*684 + f] = (f < HF_) ? dww[(size_t)f*9 + l] : 0.f;
}

// ---------------- fused softmax + x_local + x_pool -> out (bf16), parallel softmax ----
__global__ __launch_bounds__(256) void xout_v4(const float* __restrict__ qlt,
                                               const float* __restrict__ attn,
                                               const u16* __restrict__ kv,
                                               const u16* __restrict__ kvp2,
                                               u16* __restrict__ out){
  __shared__ float coef[4][472];
  int t = threadIdx.x, w = t>>6, l = t&63;
  int row = blockIdx.x*4 + w;
  int b = row / N_, n = row - b*N_;
  int y = n / WW, x = n - y*WW;
  const float* arow = attn + (size_t)row*464;
  for (int i=l; i<464; i+=64) coef[w][i] = arow[i];
  __syncthreads();
  int h = l>>3, k = l&7;
  float* ch = &coef[w][h*58];
  // per-head softmax: 8 lanes per head, shuffle-reduce within the 8-lane group
  float e[8];
  float mx = -1e30f;
  #pragma unroll
  for (int i=0;i<8;i++){
    int j = k + i*8;
    e[i] = (j<58) ? ch[j] : -1e30f;
    mx = fmaxf(mx, e[i]);
  }
  mx = fmaxf(mx, __shfl_xor(mx,1,64));
  mx = fmaxf(mx, __shfl_xor(mx,2,64));
  mx = fmaxf(mx, __shfl_xor(mx,4,64));
  float s = 0.f;
  #pragma unroll
  for (int i=0;i<8;i++){
    int j = k + i*8;
    if (j<58){ e[i] = expf(e[i]-mx); s += e[i]; }
  }
  s += __shfl_xor(s,1,64);
  s += __shfl_xor(s,2,64);
  s += __shfl_xor(s,4,64);
  float inv = 1.f/s;
  #pragma unroll
  for (int i=0;i<8;i++){
    int j = k + i*8;
    if (j<58){
      float v = e[i]*inv;
      if (j<9) v += qlt[(size_t)row*72 + h*9 + j];
      ch[j] = v;
    }
  }
  __syncthreads();
  int c = l*4;
  float a0=0.f, a1=0.f, a2=0.f, a3=0.f;
  #pragma unroll
  for (int lw=0; lw<9; lw++){
    int yy = y + lw/3 - 1, xx = x + lw%3 - 1;
    if (yy>=0 && yy<HH && xx>=0 && xx<WW){
      ushort4 vv = *(const ushort4*)(kv + ((size_t)(b*N_ + yy*WW + xx))*512 + 256 + c);
      float cf = ch[lw];
      a0 = fmaf(cf, b2f(vv.x), a0);
      a1 = fmaf(cf, b2f(vv.y), a1);
      a2 = fmaf(cf, b2f(vv.z), a2);
      a3 = fmaf(cf, b2f(vv.w), a3);
    }
  }
  const u16* pb = kvp2 + (size_t)b*PL_*512 + 256 + c;
  #pragma unroll 7
  for (int p=0;p<49;p++){
    ushort4 vv = *(const ushort4*)(pb + (size_t)p*512);
    float cf = ch[9+p];
    a0 = fmaf(cf, b2f(vv.x), a0);
    a1 = fmaf(cf, b2f(vv.y), a1);
    a2 = fmaf(cf, b2f(vv.z), a2);
    a3 = fmaf(cf, b2f(vv.w), a3);
  }
  ushort4 o; o.x=f2bf(a0); o.y=f2bf(a1); o.z=f2bf(a2); o.w=f2bf(a3);
  *(ushort4*)(out + (size_t)row*C_ + c) = o;
}

// ---------------- depthwise 3x3 + gelu gate, 8 ch/thread, XCD-confined ----------------
__global__ __launch_bounds__(256) void dwconv_v4(const u16* __restrict__ hsrc,
                                                 const float* __restrict__ dwwT,
                                                 const float* __restrict__ dwb,
                                                 u16* __restrict__ hg){
  int b = blockIdx.x;
  int idx = blockIdx.y*256 + threadIdx.x;
  if (idx >= N_*86) return;
  int n = idx/86, g = idx - n*86;
  int pix = b*N_ + n;
  int y = n / WW, x = n - y*WW;
  const u16* hb = hsrc + (size_t)b*N_*HBLD;
  if (g < 85){
    int f = g*8;
    float s[8];
    #pragma unroll
    for (int e=0;e<8;e++) s[e] = dwb[f+e];
    #pragma unroll
    for (int l=0;l<9;l++){
      int yy = y + l/3 - 1, xx = x + l%3 - 1;
      if (yy>=0 && yy<HH && xx>=0 && xx<WW){
        u16x8 hv = *(const u16x8*)(hb + (size_t)(yy*WW+xx)*HBLD + f);
        const float* wv = dwwT + (size_t)l*684 + f;
        #pragma unroll
        for (int e=0;e<8;e++) s[e] = fmaf(b2f(hv[e]), wv[e], s[e]);
      }
    }
    const u16* vp = hsrc + (size_t)pix*HBLD + HF_ + f;
    u16 ov[8];
    #pragma unroll
    for (int e=0;e<8;e++) ov[e] = f2bf(gelu_f(s[e]) * b2f(vp[e]));
    *(u16x8*)(hg + (size_t)pix*HGLD + f) = *(u16x8*)ov;
  } else {
    float r[2];
    #pragma unroll
    for (int c=0;c<2;c++){
      int ff = 680 + c;
      float s = dwb[ff];
      #pragma unroll
      for (int l=0;l<9;l++){
        int yy = y + l/3 - 1, xx = x + l%3 - 1;
        if (yy>=0 && yy<HH && xx>=0 && xx<WW)
          s += b2f(hb[(size_t)(yy*WW+xx)*HBLD + ff]) * dwwT[(size_t)l*684 + ff];
      }
      r[c] = gelu_f(s) * b2f(hsrc[(size_t)pix*HBLD + HF_ + ff]);
    }
    u16* hp = hg + (size_t)pix*HGLD;
    ushort4 o1; o1.x = f2bf(r[0]); o1.y = f2bf(r[1]); o1.z = 0; o1.w = 0;
    *(ushort4*)(hp + 680) = o1;
    ushort4 z4 = {0,0,0,0};
    *(ushort4*)(hp + 684) = z4;
    *(ushort4*)(hp + 688) = z4;
    *(ushort4*)(hp + 692) = z4;
    *(ushort4*)(hp + 696) = z4;
    *(ushort4*)(hp + 700) = z4;
  }
}

extern "C" void kernel_launch(void* const* d_in, const int* in_sizes, int n_in,
                              void* d_out, int out_size, void* d_ws, size_t ws_size,
                              hipStream_t stream) {
  const float* x    = (const float*)d_in[0];
  const float* rct  = (const float*)d_in[1];
  const float* sls  = (const float*)d_in[2];
  const float* n1w  = (const float*)d_in[3];
  const float* n1b  = (const float*)d_in[4];
  const float* q_w  = (const float*)d_in[5];
  const float* q_b  = (const float*)d_in[6];
  const float* kv_w = (const float*)d_in[7];
  const float* kv_b = (const float*)d_in[8];
  const float* temp = (const float*)d_in[9];
  const float* qe   = (const float*)d_in[10];
  const float* rpb  = (const float*)d_in[11];
  const float* lt   = (const float*)d_in[12];
  const float* lb   = (const float*)d_in[13];
  const float* sr_w = (const float*)d_in[14];
  const float* sr_b = (const float*)d_in[15];
  const float* npw  = (const float*)d_in[16];
  const float* npb  = (const float*)d_in[17];
  const float* c1w  = (const float*)d_in[18];
  const float* c1b  = (const float*)d_in[19];
  const float* c2w  = (const float*)d_in[20];
  const float* c2b  = (const float*)d_in[21];
  const float* pw   = (const float*)d_in[22];
  const float* pb   = (const float*)d_in[23];
  const float* n2w  = (const float*)d_in[24];
  const float* n2b  = (const float*)d_in[25];
  const float* f1w  = (const float*)d_in[26];
  const float* f1b  = (const float*)d_in[27];
  const float* dww  = (const float*)d_in[28];
  const float* dwb  = (const float*)d_in[29];
  const float* f2w  = (const float*)d_in[30];
  const float* f2bb = (const float*)d_in[31];
  const int*  ridx  = (const int*)d_in[32];
  float* outp = (float*)d_out;

  char* ws = (char*)d_ws;
  constexpr size_t SZ_BNC2 = (size_t)MROWS*C_*2;
  constexpr size_t SZ_KV2  = (size_t)MROWS*512*2;
  constexpr size_t SZ_ATTN = (size_t)MROWS*464*4;
  size_t o_xn   = 0;
  size_t o_qn   = o_xn   + SZ_BNC2;
  size_t o_qs   = o_qn   + SZ_BNC2;
  size_t o_kv   = o_qs   + SZ_BNC2;
  size_t o_attn = o_kv   + SZ_KV2;
  size_t o_xsr  = o_attn + SZ_ATTN;
  size_t o_xpln = o_xsr  + SZ_BNC2;
  size_t o_kvp2 = o_xpln + (size_t)B_*PL_*C_*2;
  size_t o_cpb  = o_kvp2 + (size_t)B_*PL_*512*2;
  size_t o_outb = o_cpb  + (size_t)1024*8*4;
  size_t o_x2   = o_outb + SZ_BNC2;
  size_t o_qlt  = o_x2   + (size_t)MROWS*C_*4;
  size_t o_wq   = o_qlt  + (size_t)MROWS*72*4;
  size_t o_wkv  = o_wq   + (size_t)65536*2;
  size_t o_wsr  = o_wkv  + (size_t)131072*2;
  size_t o_wp   = o_wsr  + (size_t)65536*2;
  size_t o_wf1  = o_wp   + (size_t)65536*2;
  size_t o_wf2  = o_wf1  + (size_t)349184*2;
  size_t o_w72  = o_wf2  + (size_t)256*F2LD*2;
  size_t o_dwwT = o_w72  + (size_t)72*256*2;
  size_t o_h    = o_kv;
  size_t o_hg   = 0;

  u16*   xn   = (u16*)(ws + o_xn);
  u16*   qbuf = (u16*)(ws + o_qn);
  u16*   qsc  = (u16*)(ws + o_qs);
  u16*   kv   = (u16*)(ws + o_kv);
  float* attn = (float*)(ws + o_attn);
  u16*   xsr  = (u16*)(ws + o_xsr);
  u16*   xpln = (u16*)(ws + o_xpln);
  u16*   kvp2 = (u16*)(ws + o_kvp2);
  float* cpb  = (float*)(ws + o_cpb);
  u16*   outb = (u16*)(ws + o_outb);
  float* x2   = (float*)(ws + o_x2);
  float* qlt  = (float*)(ws + o_qlt);
  u16*   wq   = (u16*)(ws + o_wq);
  u16*   wkv  = (u16*)(ws + o_wkv);
  u16*   wsr  = (u16*)(ws + o_wsr);
  u16*   wp   = (u16*)(ws + o_wp);
  u16*   wf1  = (u16*)(ws + o_wf1);
  u16*   wf2  = (u16*)(ws + o_wf2);
  u16*   w72  = (u16*)(ws + o_w72);
  float* dwwT = (float*)(ws + o_dwwT);
  u16*   hbuf = (u16*)(ws + o_h);
  u16*   hg   = (u16*)(ws + o_hg);

  // 0. weight conversions (bf16 copies)
  cvt4_kernel<<<(65536/4+255)/256, 256, 0, stream>>>(q_w,  wq,  65536/4);
  cvt4_kernel<<<(131072/4+255)/256,256, 0, stream>>>(kv_w, wkv, 131072/4);
  cvt4_kernel<<<(65536/4+255)/256, 256, 0, stream>>>(sr_w, wsr, 65536/4);
  cvt4_kernel<<<(65536/4+255)/256, 256, 0, stream>>>(pw,   wp,  65536/4);
  cvt4_kernel<<<(349184/4+255)/256,256, 0, stream>>>(f1w,  wf1, 349184/4);
  cvt_pad_kernel<<<(256*F2LD+255)/256, 256, 0, stream>>>(f2w, wf2, 256, HF_, F2LD);
  build_w72<<<72, 256, 0, stream>>>(lt, w72);
  build_dwwT<<<9, 256, 0, stream>>>(dww, dwwT);

  // 1. xn = LN(x) -> bf16
  ln_kernel<<<MROWS, 256, 0, stream>>>(x, n1w, n1b, xn);
  // 2. q = xn @ q_w^T + q_b -> bf16
  gemm64b<0,0,1><<<dim3(392,4), 256, 0, stream>>>(xn, C_, wq, C_, q_b, nullptr, qbuf, MROWS, 256, 256);
  // 3. kv = xn @ kv_w^T + kv_b -> bf16
  gemm64b<0,0,1><<<dim3(392,8), 256, 0, stream>>>(xn, C_, wkv, C_, kv_b, nullptr, kv, MROWS, 512, 256);
  // 4. q_norm (in place) + q_scaled
  qpost_kernel<<<MROWS, 256, 0, stream>>>(qbuf, qe, temp, sls, qsc);
  // 5. k l2norm in place
  knorm_kernel<<<MROWS, 256, 0, stream>>>(kv);
  // 6. x_sr = gelu(xn @ sr_w^T + sr_b) -> bf16
  gemm64b<1,0,1><<<dim3(392,4), 256, 0, stream>>>(xn, C_, wsr, C_, sr_b, nullptr, xsr, MROWS, 256, 256);
  // 7. 8x8 avg pool + LN(normp) -> bf16
  pool_ln_kernel<<<B_*PL_, 256, 0, stream>>>(xsr, npw, npb, xpln);
  // 8. kvp2 = xpln @ kv_w^T + kv_b -> bf16
  gemm64b<0,0,1><<<dim3(7,8), 256, 0, stream>>>(xpln, C_, wkv, C_, kv_b, nullptr, kvp2, B_*PL_, 512, 256);
  // 9. k_pool l2norm in place
  knorm_kernel<<<B_*PL_, 256, 0, stream>>>(kvp2);
  // 10. CPB MLP
  cpb_kernel<<<1024, 256, 0, stream>>>(rct, c1w, c1b, c2w, c2b, cpb);
  // 10b. qlt = qn @ w72^T + lb -> f32
  gemm64b<0,0,0><<<dim3(392,2), 256, 0, stream>>>(qbuf, C_, w72, C_, lb, nullptr, qlt, MROWS, 72, 256);
  // 11. local attention logits (token-major)
  attn_local_v3<<<MROWS/32, 256, 0, stream>>>(qsc, kv, rpb, attn);
  // 12. pooled attention logits (MFMA, token-major)
  attn_pool_mfma<<<dim3(49,64), 256, 0, stream>>>(qsc, kvp2, cpb, ridx, attn);
  // 13+14. fused softmax + x_local + x_pool -> outb bf16 (parallel softmax)
  xout_v4<<<MROWS/4, 256, 0, stream>>>(qlt, attn, kv, kvp2, outb);
  // 15. x2 = x + outb @ proj_w^T + proj_b -> f32
  gemm64b<0,1,0><<<dim3(392,4), 256, 0, stream>>>(outb, C_, wp, C_, pb, x, x2, MROWS, 256, 256);
  // 16. xn2 = LN(x2) -> bf16 (reuses xn)
  ln_kernel<<<MROWS, 256, 0, stream>>>(x2, n2w, n2b, xn);
  // 17. h = xn2 @ fc1_w^T + fc1_b -> bf16 (ldo=HBLD, async 128-tile)
  gemm128a<<<dim3(196,11), 256, 0, stream>>>(xn, C_, wf1, C_, f1b, hbuf, MROWS, 1364, 256, HBLD);
  // 18. hg = gelu(dwconv(h1)+dwb) * v -> bf16 (8 ch/thread, XCD-confined)
  dwconv_v4<<<dim3(8, (N_*86+255)/256), 256, 0, stream>>>(hbuf, dwwT, dwb, hg);
  // 19. out = x2 + hg @ fc2_w^T + fc2_b -> f32
  gemm64b<0,1,0><<<dim3(392,4), 256, 0, stream>>>(hg, HGLD, wf2, F2LD, f2bb, x2, outp, MROWS, 256, HF_);
}